// Round 6
// baseline (619.472 us; speedup 1.0000x reference)
//
#include <hip/hip_runtime.h>
#include <math.h>

#define NB 32
#define PP 24564
#define MM 32
#define NCLS 81
#define CHUNK 1024
#define MBLK 24          // ceil(PP/CHUNK)
#define PPW 768          // posbit u32 words per image
#define POSX 64          // k_posneg blocks per image
#define SLICE 384        // ceil(PP/POSX)
#define PROW (MBLK*CHUNK + MM)
#define BINS 2048
#define BSH 21           // bin = float_bits >> 21 (top 11 bits)
#define CAP 4096         // per-image candidate list capacity
#define SKIPB 0xFFFFFFFFu

// ---- workspace layout (bytes) ----
#define WS_ACC    0        // float[4]: 0=loc 1=ce 2=objpos 3=hardneg
#define WS_DONE   16       // int
#define WS_SELD   32       // u32[NB] threshold bin (SKIPB = no refine)
#define WS_SELR   160      // int[NB] rem within threshold bin
#define WS_ARR    288      // int[NB] arrival counters
#define WS_CCNT   416      // int[NB] candidate counts
#define WS_PCNT   544      // int[NB]
#define WS_ECNT   672      // int[NB]
#define WS_CPART  800      // int[NB*MBLK]
#define WS_FLIST  3968     // u32[NB*MM]
#define WS_BKEYP  8192     // u64[NB*MBLK*MM]
#define WS_POSBIT 204800   // u32[NB*PPW]
#define WS_PLIST  303104   // u32[NB*PROW]
#define WS_HIST   3452928  // u32[NB*BINS]
#define WS_BSUM   3715072  // float[NB*BINS]
#define WS_CLIST  3977216  // u32[NB*CAP]
#define ZERO_HDR_WORDS 136           // [0,544): acc,done,seld,selr,arr,ccnt
#define ZERO_HIST_WORDS (NB*BINS*2)  // hist + bsum

__device__ __forceinline__ float sl1(float d) {
    float a = fabsf(d);
    return a < 1.0f ? 0.5f * d * d : a - 0.5f;
}
__device__ __forceinline__ unsigned long long u64max(unsigned long long a, unsigned long long b) {
    return a > b ? a : b;
}

// ---------- zero counters + histograms ----------
extern "C" __global__ void __launch_bounds__(256) k_zero(unsigned* __restrict__ ws) {
    int i = blockIdx.x * 256 + threadIdx.x;
    if (i < ZERO_HDR_WORDS) ws[i] = 0;
    unsigned* h = ws + WS_HIST / 4;
    for (int j = i; j < ZERO_HIST_WORDS; j += gridDim.x * 256) h[j] = 0;
}

// ---------- matching + per-image value histogram ----------
extern "C" __global__ void __launch_bounds__(256) k_match(
    const float* __restrict__ priors,
    const float* __restrict__ boxes,
    const float* __restrict__ obj,
    unsigned long long* __restrict__ bkeyp,
    unsigned int* __restrict__ posbit,
    unsigned int* __restrict__ plist,
    int* __restrict__ cpart,
    unsigned int* __restrict__ hist,
    float* __restrict__ bsum)
{
    const int n = blockIdx.y;
    const int t = threadIdx.x;
    const int lane = t & 63;
    const int wave = t >> 6;
    const int bx = blockIdx.x;
    const int p0 = bx * CHUNK;

    __shared__ float4 spri[CHUNK];
    __shared__ float bx0[MM], by0[MM], bx1[MM], by1[MM], bar_[MM];
    __shared__ unsigned long long wk[4][MM];
    __shared__ int bcnt;
    __shared__ unsigned int lh[BINS];
    __shared__ float lb[BINS];

    for (int i = t; i < BINS; i += 256) { lh[i] = 0; lb[i] = 0.f; }

    float ov[4];
#pragma unroll
    for (int i = 0; i < 4; i++) {
        int p = p0 + t + i * 256;
        float4 v;
        if (p < PP) { v = *(const float4*)(priors + (size_t)p * 4);
                      ov[i] = obj[(size_t)n * PP + p]; }
        else { v.x = 3.f; v.y = 3.f; v.z = 3.5f; v.w = 3.5f; ov[i] = 0.f; }
        spri[t + i * 256] = v;
    }
    if (t < MM) {
        const float* b = boxes + ((size_t)n * MM + t) * 4;
        float x1 = b[0], y1 = b[1], x2 = b[2], y2 = b[3];
        bx0[t] = x1; by0[t] = y1; bx1[t] = x2; by1[t] = y2;
        bar_[t] = (x2 - x1) * (y2 - y1);
    }
    if (t == 0) bcnt = 0;
    __syncthreads();

    float4 pr0 = spri[t], pr1 = spri[t + 256], pr2 = spri[t + 512], pr3 = spri[t + 768];
    const float pa0 = (pr0.z - pr0.x) * (pr0.w - pr0.y);
    const float pa1 = (pr1.z - pr1.x) * (pr1.w - pr1.y);
    const float pa2 = (pr2.z - pr2.x) * (pr2.w - pr2.y);
    const float pa3 = (pr3.z - pr3.x) * (pr3.w - pr3.y);
    unsigned pb0 = 0, pb1 = 0, pb2 = 0, pb3 = 0;

#define DO_IOU(PR, PA, PB, ROFF) { \
        float w = fminf(x1, PR.z) - fmaxf(x0, PR.x); \
        float h = fminf(y1, PR.w) - fmaxf(y0, PR.y); \
        w = fmaxf(w, 0.0f); h = fmaxf(h, 0.0f); \
        float inter = w * h; \
        float iou = inter / (ar + PA - inter); \
        unsigned ib = __float_as_uint(iou); \
        unsigned nk = (ib & 0xFFFFFFE0u) | (unsigned)(31 - m); \
        PB = PB > nk ? PB : nk; \
        unsigned long long kk = ((unsigned long long)ib << 32) \
            | (unsigned long long)(0xFFFFFFFFu - (unsigned)(p0 + t + (ROFF))); \
        km = u64max(km, kk); }

#pragma unroll 2
    for (int m = 0; m < MM; m++) {
        const float x0 = bx0[m], y0 = by0[m], x1 = bx1[m], y1 = by1[m], ar = bar_[m];
        unsigned long long km = 0ULL;
        DO_IOU(pr0, pa0, pb0, 0)
        DO_IOU(pr1, pa1, pb1, 256)
        DO_IOU(pr2, pa2, pb2, 512)
        DO_IOU(pr3, pa3, pb3, 768)
#pragma unroll
        for (int d = 1; d < 64; d <<= 1)
            km = u64max(km, (unsigned long long)__shfl_xor(km, d));
        if (lane == 0) wk[wave][m] = km;
    }
#undef DO_IOU

    const unsigned long long lm = (1ULL << lane) - 1ULL;
    unsigned long long bl[4]; bool pf[4]; unsigned pv[4]; int cw[4];
#define ROWOUT(PB, R) { \
        int p = p0 + t + (R) * 256; \
        bool pos = (PB >= 0x3F000000u) && (p < PP); \
        unsigned long long ball = __ballot(pos); \
        if (lane == 0) { \
            int wi = n * PPW + ((p0 + (R) * 256 + wave * 64) >> 5); \
            posbit[wi] = (unsigned)ball; posbit[wi + 1] = (unsigned)(ball >> 32); \
        } \
        bl[R] = ball; pf[R] = pos; cw[R] = __popcll(ball); \
        pv[R] = (unsigned)p | ((31u - (PB & 31u)) << 16); \
        if (p < PP) { \
            float v = pos ? 0.f : ov[R] * ov[R]; \
            unsigned bn = __float_as_uint(v) >> BSH; \
            atomicAdd(&lh[bn], 1u); \
            atomicAdd(&lb[bn], v); \
        } }
    ROWOUT(pb0, 0) ROWOUT(pb1, 1) ROWOUT(pb2, 2) ROWOUT(pb3, 3)
#undef ROWOUT

    int tot = cw[0] + cw[1] + cw[2] + cw[3];
    int wbase = 0;
    if (lane == 0 && tot) wbase = atomicAdd(&bcnt, tot);
    wbase = __shfl(wbase, 0);
    unsigned* pl = plist + (size_t)n * PROW + (size_t)bx * CHUNK;
    int b = wbase;
#pragma unroll
    for (int r = 0; r < 4; r++) {
        if (pf[r]) pl[b + __popcll(bl[r] & lm)] = pv[r];
        b += cw[r];
    }

    __syncthreads();
    if (t == 0) cpart[n * MBLK + bx] = bcnt;
    if (t < MM) {
        unsigned long long r = u64max(u64max(wk[0][t], wk[1][t]),
                                      u64max(wk[2][t], wk[3][t]));
        bkeyp[((size_t)n * MBLK + bx) * MM + t] = r;
    }
    // flush histogram to global
    for (int i = t; i < BINS; i += 256) {
        unsigned c = lh[i];
        if (c) atomicAdd(&hist[n * BINS + i], c);
        float s = lb[i];
        if (s != 0.f) atomicAdd(&bsum[n * BINS + i], s);
    }
}

// ---------- forced overrides + totals + bin-level selection ----------
extern "C" __global__ void __launch_bounds__(1024) k_force(
    const float* __restrict__ obj,
    const unsigned long long* __restrict__ bkeyp,
    const int* __restrict__ cpart,
    unsigned int* __restrict__ flist,
    unsigned int* __restrict__ posbit,
    unsigned int* __restrict__ plist,
    int* __restrict__ pcnt,
    int* __restrict__ ecnt,
    unsigned int* __restrict__ hist,
    float* __restrict__ bsum,
    unsigned int* __restrict__ seld,
    int* __restrict__ selr,
    float* __restrict__ acc)
{
    const int t = threadIdx.x;          // 1024 = NB*MM
    __shared__ int lecnt[NB];
    __shared__ int spcnt[NB];
    if (t < NB) lecnt[t] = 0;
    __syncthreads();

    const int n = t >> 5, m = t & 31;
    const unsigned long long* bp = bkeyp + (size_t)n * MBLK * MM + m;
    unsigned long long r = 0ULL;
#pragma unroll
    for (int s = 0; s < MBLK; s++) r = u64max(r, bp[(size_t)s * MM]);
    unsigned p = 0xFFFFFFFFu - (unsigned)(r & 0xFFFFFFFFULL);
    flist[t] = p;
    unsigned bit = 1u << (p & 31);
    unsigned old = atomicOr(&posbit[n * PPW + (p >> 5)], bit);
    if (!(old & bit)) {
        int slot = atomicAdd(&lecnt[n], 1);
        plist[(size_t)n * PROW + MBLK * CHUNK + slot] = p | ((unsigned)m << 16);
        float o = obj[(size_t)n * PP + p];
        float v = o * o;
        unsigned bn = __float_as_uint(v) >> BSH;
        atomicSub(&hist[n * BINS + bn], 1u);
        atomicAdd(&hist[n * BINS + 0], 1u);     // value becomes 0 -> bin 0
        atomicAdd(&bsum[n * BINS + bn], -v);
    }
    __syncthreads();
    if (t < NB) {
        int e = lecnt[t]; ecnt[t] = e;
        int tot = e;
        for (int b = 0; b < MBLK; b++) tot += cpart[t * MBLK + b];
        pcnt[t] = tot; spcnt[t] = tot;
    }
    __threadfence();
    __syncthreads();

    // ---- selection: 32 lanes per image, descending 64-bin stripes ----
    const int sl = t & 31;
    int k = spcnt[n] * 3; if (k > PP) k = PP;
    const unsigned* hn = hist + n * BINS;
    const float* sn = bsum + n * BINS;
    const int top = 2047 - sl * 64;
    unsigned c = 0; float s = 0.f;
    for (int b = top; b > top - 64; --b) { c += hn[b]; s += sn[b]; }
    int ic = (int)c; float isf = s;
#pragma unroll
    for (int d2 = 1; d2 < 32; d2 <<= 1) {
        int vc = __shfl_up(ic, d2, 32);
        float vs = __shfl_up(isf, d2, 32);
        if (sl >= d2) { ic += vc; isf += vs; }
    }
    int exc = ic - (int)c; float exs = isf - s;

    if (k <= 0) {
        if (sl == 0) seld[n] = SKIPB;
    } else if (k >= PP) {
        float totsum = __shfl(isf, 31, 32);
        if (sl == 0) { seld[n] = SKIPB; atomicAdd(&acc[3], totsum); }
    } else if (exc < k && ic >= k) {
        int cum = exc; float sa = exs; int d = -1; int rem = 0;
        for (int b = top; b > top - 64; --b) {
            int hb = (int)hn[b];
            if (cum + hb >= k) { d = b; rem = k - cum; break; }
            cum += hb; sa += sn[b];
        }
        atomicAdd(&acc[3], sa);
        if (d > 0) { seld[n] = (unsigned)d; selr[n] = rem; }
        else seld[n] = SKIPB;   // threshold in bin 0: values ~0, contribution negligible
    }
}

// ---------- positive losses + candidate collect + per-image refine + finalize ----------
extern "C" __global__ void __launch_bounds__(256) k_posneg(
    const float* __restrict__ pred_boxes,
    const float* __restrict__ pred_cls,
    const float* __restrict__ pred_obj,
    const float* __restrict__ priors,
    const float* __restrict__ boxes,
    const int* __restrict__ labels,
    const unsigned int* __restrict__ plist,
    const unsigned int* __restrict__ flist,
    const unsigned int* __restrict__ posbit,
    const int* __restrict__ cpart,
    const int* __restrict__ ecnt,
    const int* __restrict__ pcnt,
    const unsigned int* __restrict__ seld,
    const int* __restrict__ selr,
    unsigned int* __restrict__ clist,
    int* __restrict__ ccnt,
    int* __restrict__ arrive,
    float* __restrict__ acc,
    int* __restrict__ done,
    float* __restrict__ out)
{
    const int n = blockIdx.y;
    const int t = threadIdx.x;
    const int lane = t & 63;
    const int wave = t >> 6;

    __shared__ unsigned fl[MM];
    __shared__ int pref[MBLK + 2];
    __shared__ float sacc[4];
    __shared__ unsigned lv[CAP];
    __shared__ unsigned rhist[128];
    __shared__ unsigned s_cur;
    __shared__ int s_rem;
    __shared__ int s_last;
    __shared__ float rs, rc;

    if (t < MM) fl[t] = flist[n * MM + t];
    if (t < 4) sacc[t] = 0.f;
    if (t == 0) {
        int a = 0;
        for (int s = 0; s < MBLK; s++) { pref[s] = a; a += cpart[n * MBLK + s]; }
        pref[MBLK] = a;
        pref[MBLK + 1] = a + ecnt[n];
    }
    __syncthreads();
    const int T = pref[MBLK + 1];
    const unsigned dbin = seld[n];

    // ---- positive-prior losses ----
    {
        const unsigned* pl = plist + (size_t)n * PROW;
        float ce_s = 0.f, loc_s = 0.f, op_s = 0.f;
        for (int i = blockIdx.x * 4 + wave; i < T; i += POSX * 4) {
            int s = 0;
            while (pref[s + 1] <= i) s++;
            int slot = (s < MBLK) ? s * CHUNK + (i - pref[s])
                                  : MBLK * CHUNK + (i - pref[MBLK]);
            const unsigned e = pl[slot];
            const int p = (int)(e & 0xFFFFu);
            int bm = (int)((e >> 16) & 31u);
#pragma unroll
            for (int j = 0; j < MM; j++)
                if (fl[j] == (unsigned)p) bm = j;
            const size_t idx = (size_t)n * PP + p;

            const float* row = pred_cls + idx * NCLS;
            float a = row[lane];
            float b = (lane < NCLS - 64) ? row[lane + 64] : -INFINITY;
            float mx = fmaxf(a, b);
#pragma unroll
            for (int d = 1; d < 64; d <<= 1) mx = fmaxf(mx, __shfl_xor(mx, d));
            float se = expf(a - mx) + ((lane < NCLS - 64) ? expf(b - mx) : 0.f);
#pragma unroll
            for (int d = 1; d < 64; d <<= 1) se += __shfl_xor(se, d);

            if (lane == 0) {
                int lb = labels[n * MM + bm];
                ce_s += mx + logf(se) - row[lb];
            } else if (lane == 1) {
                float4 pb = *(const float4*)(priors + (size_t)p * 4);
                const float* bb = boxes + ((size_t)n * MM + bm) * 4;
                float gx1 = bb[0], gy1 = bb[1], gx2 = bb[2], gy2 = bb[3];
                float pcx = (pb.x + pb.z) * 0.5f, pcy = (pb.y + pb.w) * 0.5f;
                float pw = pb.z - pb.x, ph = pb.w - pb.y;
                float g0 = ((gx1 + gx2) * 0.5f - pcx) / (pw / 10.0f);
                float g1 = ((gy1 + gy2) * 0.5f - pcy) / (ph / 10.0f);
                float g2 = logf((gx2 - gx1) / pw) * 5.0f;
                float g3 = logf((gy2 - gy1) / ph) * 5.0f;
                float4 pd = *(const float4*)(pred_boxes + idx * 4);
                loc_s += sl1(pd.x - g0) + sl1(pd.y - g1) + sl1(pd.z - g2) + sl1(pd.w - g3);
            } else if (lane == 2) {
                float o = pred_obj[idx];
                op_s += (o - 1.0f) * (o - 1.0f);
            }
        }
        if (lane == 0 && ce_s != 0.f)  atomicAdd(&sacc[0], ce_s);
        if (lane == 1 && loc_s != 0.f) atomicAdd(&sacc[1], loc_s);
        if (lane == 2 && op_s != 0.f)  atomicAdd(&sacc[2], op_s);
    }

    // ---- collect bin-d candidates from this block's slice ----
    if (dbin != SKIPB) {
        const int base = blockIdx.x * SLICE;
        for (int j = t; j < SLICE; j += 256) {
            int p = base + j;
            if (p >= PP) break;
            unsigned msk = (posbit[n * PPW + (p >> 5)] >> (p & 31)) & 1u;
            float o = pred_obj[(size_t)n * PP + p];
            float v = msk ? 0.f : o * o;
            unsigned bits = __float_as_uint(v);
            if ((bits >> BSH) == dbin) {
                int idx = atomicAdd(&ccnt[n], 1);
                if (idx < CAP) clist[(size_t)n * CAP + idx] = bits;
            }
        }
    }

    __syncthreads();
    if (t == 0) {
        if (sacc[0] != 0.f) atomicAdd(&acc[1], sacc[0]);
        if (sacc[1] != 0.f) atomicAdd(&acc[0], sacc[1]);
        if (sacc[2] != 0.f) atomicAdd(&acc[2], sacc[2]);
        __threadfence();
        int a = atomicAdd(&arrive[n], 1);
        s_last = (a == POSX - 1);
    }
    __syncthreads();

    // ---- last block of image n: refine within threshold bin ----
    if (s_last && dbin != SKIPB) {
        const int C = ccnt[n];
        const int rem0 = selr[n];
        const bool lds_ok = (C <= CAP);
        if (lds_ok)
            for (int i = t; i < C; i += 256) lv[i] = clist[(size_t)n * CAP + i];
        if (t == 0) { rs = 0.f; rc = 0.f; }
        __syncthreads();

        auto visit = [&](auto&& fn) {
            if (lds_ok) {
                for (int i = t; i < C; i += 256) fn(lv[i]);
            } else {
                for (int p2 = t; p2 < PP; p2 += 256) {
                    unsigned msk = (posbit[n * PPW + (p2 >> 5)] >> (p2 & 31)) & 1u;
                    float o = pred_obj[(size_t)n * PP + p2];
                    float v = msk ? 0.f : o * o;
                    unsigned bits = __float_as_uint(v);
                    if ((bits >> BSH) == dbin) fn(bits);
                }
            }
        };

        unsigned cur = dbin << BSH;
        int rem = rem0;
        for (int pass = 0; pass < 3; ++pass) {
            const int sh = 14 - 7 * pass;
            for (int i = t; i < 128; i += 256) rhist[i] = 0;
            __syncthreads();
            visit([&](unsigned b) {
                if ((b >> (sh + 7)) == (cur >> (sh + 7)))
                    atomicAdd(&rhist[(b >> sh) & 127u], 1u);
            });
            __syncthreads();
            if (t == 0) {
                int cum = 0; int dd;
                for (dd = 127; dd > 0; --dd) {
                    int h = (int)rhist[dd];
                    if (cum + h >= rem) break;
                    cum += h;
                }
                s_cur = cur | ((unsigned)dd << sh);
                s_rem = rem - cum;
            }
            __syncthreads();
            cur = s_cur; rem = s_rem;
        }
        const unsigned thr = cur;
        const float thrv = __uint_as_float(thr);
        float ms = 0.f, mc = 0.f;
        visit([&](unsigned b) {
            if (b > thr) { ms += __uint_as_float(b); mc += 1.f; }
        });
#pragma unroll
        for (int d = 32; d > 0; d >>= 1) {
            ms += __shfl_down(ms, d);
            mc += __shfl_down(mc, d);
        }
        if (lane == 0) { atomicAdd(&rs, ms); atomicAdd(&rc, mc); }
        __syncthreads();
        if (t == 0)
            atomicAdd(&acc[3], rs + ((float)rem0 - rc) * thrv);
    }
    __syncthreads();

    // ---- grid-wide completion: last block finalizes ----
    if (t == 0) {
        __threadfence();
        int old = atomicAdd(done, 1);
        if (old == POSX * NB - 1) {
            float a0 = atomicAdd(&acc[0], 0.f);
            float a1 = atomicAdd(&acc[1], 0.f);
            float a2 = atomicAdd(&acc[2], 0.f);
            float a3 = atomicAdd(&acc[3], 0.f);
            int np = 0, den = 0;
            for (int i = 0; i < NB; i++) {
                int cc = pcnt[i];
                np += cc;
                int kk = cc * 3; if (kk > PP) kk = PP;
                den += kk;
            }
            float npf = (float)np;
            out[0] = a1 / npf + a2 / npf
                   + a3 / fmaxf((float)den, 1.0f)
                   + a0 / (npf * 4.0f);
        }
    }
}

extern "C" void kernel_launch(void* const* d_in, const int* in_sizes, int n_in,
                              void* d_out, int out_size, void* d_ws, size_t ws_size,
                              hipStream_t stream) {
    const float* pred_boxes = (const float*)d_in[0];
    const float* pred_cls   = (const float*)d_in[1];
    const float* pred_obj   = (const float*)d_in[2];
    const float* priors     = (const float*)d_in[3];
    const float* boxes      = (const float*)d_in[4];
    const int*   labels     = (const int*)d_in[5];

    char* ws = (char*)d_ws;
    float* acc = (float*)(ws + WS_ACC);
    int* done  = (int*)(ws + WS_DONE);
    unsigned* seld = (unsigned*)(ws + WS_SELD);
    int* selr  = (int*)(ws + WS_SELR);
    int* arr   = (int*)(ws + WS_ARR);
    int* ccnt  = (int*)(ws + WS_CCNT);
    int* pcnt  = (int*)(ws + WS_PCNT);
    int* ecnt  = (int*)(ws + WS_ECNT);
    int* cpart = (int*)(ws + WS_CPART);
    unsigned* flist = (unsigned*)(ws + WS_FLIST);
    unsigned long long* bkeyp = (unsigned long long*)(ws + WS_BKEYP);
    unsigned* posbit = (unsigned*)(ws + WS_POSBIT);
    unsigned* plist = (unsigned*)(ws + WS_PLIST);
    unsigned* hist = (unsigned*)(ws + WS_HIST);
    float* bsum = (float*)(ws + WS_BSUM);
    unsigned* clist = (unsigned*)(ws + WS_CLIST);

    k_zero<<<128, 256, 0, stream>>>((unsigned*)d_ws);
    k_match<<<dim3(MBLK, NB), 256, 0, stream>>>(priors, boxes, pred_obj, bkeyp,
                                                posbit, plist, cpart, hist, bsum);
    k_force<<<1, 1024, 0, stream>>>(pred_obj, bkeyp, cpart, flist, posbit, plist,
                                    pcnt, ecnt, hist, bsum, seld, selr, acc);
    k_posneg<<<dim3(POSX, NB), 256, 0, stream>>>(pred_boxes, pred_cls, pred_obj,
                                                 priors, boxes, labels, plist, flist,
                                                 posbit, cpart, ecnt, pcnt, seld, selr,
                                                 clist, ccnt, arr, acc, done,
                                                 (float*)d_out);
}

// Round 7
// 240.920 us; speedup vs baseline: 2.5713x; 2.5713x over previous
//
#include <hip/hip_runtime.h>
#include <math.h>

#define NB 32
#define PP 24564
#define MM 32
#define NCLS 81
#define CHUNK 1024
#define MBLK 24          // ceil(PP/CHUNK)
#define PPW 768          // posbit u32 words per image
#define POSX 64          // k_pos blocks per image
#define PROW (MBLK*CHUNK + MM)
#define BINS 2048
#define BSH 21           // bin = float_bits >> 21 (top 11 bits)
#define CAPL 6144        // k_refine LDS candidate capacity
#define SKIPB 0xFFFFFFFFu

// ---- workspace layout (bytes) ----
#define WS_ACC    0        // float[4]: 0=loc 1=ce 2=objpos 3=hardneg   (zeroed)
#define WS_SELD   32       // u32[NB] threshold bin (k_force writes all)
#define WS_SELR   160      // int[NB] rem within threshold bin
#define WS_PCNT   288      // int[NB]  (k_force writes all)
#define WS_ECNT   416      // int[NB]  (k_force writes all)
#define WS_CPART  544      // int[NB*MBLK] (k_match writes all)
#define WS_FLIST  3648     // u32[NB*MM] (k_force writes all)
#define WS_BKEYP  8192     // u64[NB*MBLK*MM] (k_match writes all)
#define WS_POSBIT 204800   // u32[NB*PPW] (k_match writes all; k_force ORs)
#define WS_PLIST  303104   // u32[NB*PROW]
#define WS_HIST   3452928  // u32[NB*BINS]   (zeroed)
#define WS_BSUM   3715072  // float[NB*BINS] (zeroed)
#define ZERO_HIST_WORDS (NB*BINS*2)

__device__ __forceinline__ float sl1(float d) {
    float a = fabsf(d);
    return a < 1.0f ? 0.5f * d * d : a - 0.5f;
}
__device__ __forceinline__ unsigned long long u64max(unsigned long long a, unsigned long long b) {
    return a > b ? a : b;
}

// ---------- zero acc + histograms ----------
extern "C" __global__ void __launch_bounds__(256) k_zero(unsigned* __restrict__ ws) {
    int i = blockIdx.x * 256 + threadIdx.x;
    if (i < 4) ws[i] = 0;                       // acc
    unsigned* h = ws + WS_HIST / 4;
    for (int j = i; j < ZERO_HIST_WORDS; j += gridDim.x * 256) h[j] = 0;
}

// ---------- matching + per-image value histogram ----------
extern "C" __global__ void __launch_bounds__(256) k_match(
    const float* __restrict__ priors,
    const float* __restrict__ boxes,
    const float* __restrict__ obj,
    unsigned long long* __restrict__ bkeyp,
    unsigned int* __restrict__ posbit,
    unsigned int* __restrict__ plist,
    int* __restrict__ cpart,
    unsigned int* __restrict__ hist,
    float* __restrict__ bsum)
{
    const int n = blockIdx.y;
    const int t = threadIdx.x;
    const int lane = t & 63;
    const int wave = t >> 6;
    const int bx = blockIdx.x;
    const int p0 = bx * CHUNK;

    __shared__ float4 spri[CHUNK];
    __shared__ float bx0[MM], by0[MM], bx1[MM], by1[MM], bar_[MM];
    __shared__ unsigned long long wk[4][MM];
    __shared__ int bcnt;
    __shared__ unsigned int lh[BINS];
    __shared__ float lb[BINS];

    for (int i = t; i < BINS; i += 256) { lh[i] = 0; lb[i] = 0.f; }

    float ov[4];
#pragma unroll
    for (int i = 0; i < 4; i++) {
        int p = p0 + t + i * 256;
        float4 v;
        if (p < PP) { v = *(const float4*)(priors + (size_t)p * 4);
                      ov[i] = obj[(size_t)n * PP + p]; }
        else { v.x = 3.f; v.y = 3.f; v.z = 3.5f; v.w = 3.5f; ov[i] = 0.f; }
        spri[t + i * 256] = v;
    }
    if (t < MM) {
        const float* b = boxes + ((size_t)n * MM + t) * 4;
        float x1 = b[0], y1 = b[1], x2 = b[2], y2 = b[3];
        bx0[t] = x1; by0[t] = y1; bx1[t] = x2; by1[t] = y2;
        bar_[t] = (x2 - x1) * (y2 - y1);
    }
    if (t == 0) bcnt = 0;
    __syncthreads();

    float4 pr0 = spri[t], pr1 = spri[t + 256], pr2 = spri[t + 512], pr3 = spri[t + 768];
    const float pa0 = (pr0.z - pr0.x) * (pr0.w - pr0.y);
    const float pa1 = (pr1.z - pr1.x) * (pr1.w - pr1.y);
    const float pa2 = (pr2.z - pr2.x) * (pr2.w - pr2.y);
    const float pa3 = (pr3.z - pr3.x) * (pr3.w - pr3.y);
    unsigned pb0 = 0, pb1 = 0, pb2 = 0, pb3 = 0;   // per-prior keys: trunc-iou | (31-m)

#define DO_IOU(PR, PA, PB, ROFF) { \
        float w = fminf(x1, PR.z) - fmaxf(x0, PR.x); \
        float h = fminf(y1, PR.w) - fmaxf(y0, PR.y); \
        w = fmaxf(w, 0.0f); h = fmaxf(h, 0.0f); \
        float inter = w * h; \
        float iou = inter / (ar + PA - inter); \
        unsigned ib = __float_as_uint(iou); \
        unsigned nk = (ib & 0xFFFFFFE0u) | (unsigned)(31 - m); \
        PB = PB > nk ? PB : nk; \
        unsigned long long kk = ((unsigned long long)ib << 32) \
            | (unsigned long long)(0xFFFFFFFFu - (unsigned)(p0 + t + (ROFF))); \
        km = u64max(km, kk); }

#pragma unroll 2
    for (int m = 0; m < MM; m++) {
        const float x0 = bx0[m], y0 = by0[m], x1 = bx1[m], y1 = by1[m], ar = bar_[m];
        unsigned long long km = 0ULL;
        DO_IOU(pr0, pa0, pb0, 0)
        DO_IOU(pr1, pa1, pb1, 256)
        DO_IOU(pr2, pa2, pb2, 512)
        DO_IOU(pr3, pa3, pb3, 768)
#pragma unroll
        for (int d = 1; d < 64; d <<= 1)
            km = u64max(km, (unsigned long long)__shfl_xor(km, d));
        if (lane == 0) wk[wave][m] = km;
    }
#undef DO_IOU

    const unsigned long long lm = (1ULL << lane) - 1ULL;
    unsigned long long bl[4]; bool pf[4]; unsigned pv[4]; int cw[4];
#define ROWOUT(PB, R) { \
        int p = p0 + t + (R) * 256; \
        bool pos = (PB >= 0x3F000000u) && (p < PP); \
        unsigned long long ball = __ballot(pos); \
        if (lane == 0) { \
            int wi = n * PPW + ((p0 + (R) * 256 + wave * 64) >> 5); \
            posbit[wi] = (unsigned)ball; posbit[wi + 1] = (unsigned)(ball >> 32); \
        } \
        bl[R] = ball; pf[R] = pos; cw[R] = __popcll(ball); \
        pv[R] = (unsigned)p | ((31u - (PB & 31u)) << 16); \
        if (p < PP) { \
            float v = pos ? 0.f : ov[R] * ov[R]; \
            unsigned bn = __float_as_uint(v) >> BSH; \
            atomicAdd(&lh[bn], 1u); \
            atomicAdd(&lb[bn], v); \
        } }
    ROWOUT(pb0, 0) ROWOUT(pb1, 1) ROWOUT(pb2, 2) ROWOUT(pb3, 3)
#undef ROWOUT

    int tot = cw[0] + cw[1] + cw[2] + cw[3];
    int wbase = 0;
    if (lane == 0 && tot) wbase = atomicAdd(&bcnt, tot);
    wbase = __shfl(wbase, 0);
    unsigned* pl = plist + (size_t)n * PROW + (size_t)bx * CHUNK;
    int b = wbase;
#pragma unroll
    for (int r = 0; r < 4; r++) {
        if (pf[r]) pl[b + __popcll(bl[r] & lm)] = pv[r];
        b += cw[r];
    }

    __syncthreads();
    if (t == 0) cpart[n * MBLK + bx] = bcnt;
    if (t < MM) {
        unsigned long long r = u64max(u64max(wk[0][t], wk[1][t]),
                                      u64max(wk[2][t], wk[3][t]));
        bkeyp[((size_t)n * MBLK + bx) * MM + t] = r;
    }
    for (int i = t; i < BINS; i += 256) {
        unsigned c = lh[i];
        if (c) atomicAdd(&hist[n * BINS + i], c);
        float s = lb[i];
        if (s != 0.f) atomicAdd(&bsum[n * BINS + i], s);
    }
}

// ---------- forced overrides + totals + bin-level selection (1 block) ----------
extern "C" __global__ void __launch_bounds__(1024) k_force(
    const float* __restrict__ obj,
    const unsigned long long* __restrict__ bkeyp,
    const int* __restrict__ cpart,
    unsigned int* __restrict__ flist,
    unsigned int* __restrict__ posbit,
    unsigned int* __restrict__ plist,
    int* __restrict__ pcnt,
    int* __restrict__ ecnt,
    unsigned int* __restrict__ hist,
    float* __restrict__ bsum,
    unsigned int* __restrict__ seld,
    int* __restrict__ selr,
    float* __restrict__ acc)
{
    const int t = threadIdx.x;          // 1024 = NB*MM
    __shared__ int lecnt[NB];
    __shared__ int spcnt[NB];
    if (t < NB) lecnt[t] = 0;
    __syncthreads();

    const int n = t >> 5, m = t & 31;
    const unsigned long long* bp = bkeyp + (size_t)n * MBLK * MM + m;
    unsigned long long r = 0ULL;
#pragma unroll
    for (int s = 0; s < MBLK; s++) r = u64max(r, bp[(size_t)s * MM]);
    unsigned p = 0xFFFFFFFFu - (unsigned)(r & 0xFFFFFFFFULL);
    flist[t] = p;
    unsigned bit = 1u << (p & 31);
    unsigned old = atomicOr(&posbit[n * PPW + (p >> 5)], bit);
    if (!(old & bit)) {
        int slot = atomicAdd(&lecnt[n], 1);
        plist[(size_t)n * PROW + MBLK * CHUNK + slot] = p | ((unsigned)m << 16);
        float o = obj[(size_t)n * PP + p];
        float v = o * o;
        unsigned bn = __float_as_uint(v) >> BSH;
        atomicSub(&hist[n * BINS + bn], 1u);
        atomicAdd(&hist[n * BINS + 0], 1u);     // value becomes 0 -> bin 0
        atomicAdd(&bsum[n * BINS + bn], -v);
    }
    __syncthreads();
    if (t < NB) {
        int e = lecnt[t]; ecnt[t] = e;
        int tot = e;
        for (int b = 0; b < MBLK; b++) tot += cpart[t * MBLK + b];
        pcnt[t] = tot; spcnt[t] = tot;
    }
    __threadfence();
    __syncthreads();

    // ---- selection: 32 lanes per image, descending 64-bin stripes ----
    const int sl = t & 31;
    int k = spcnt[n] * 3; if (k > PP) k = PP;
    const unsigned* hn = hist + n * BINS;
    const float* sn = bsum + n * BINS;
    const int top = 2047 - sl * 64;
    unsigned c = 0; float s = 0.f;
    for (int b = top; b > top - 64; --b) { c += hn[b]; s += sn[b]; }
    int ic = (int)c; float isf = s;
#pragma unroll
    for (int d2 = 1; d2 < 32; d2 <<= 1) {
        int vc = __shfl_up(ic, d2, 32);
        float vs = __shfl_up(isf, d2, 32);
        if (sl >= d2) { ic += vc; isf += vs; }
    }
    int exc = ic - (int)c; float exs = isf - s;

    if (k <= 0) {
        if (sl == 0) seld[n] = SKIPB;
    } else if (k >= PP) {
        float totsum = __shfl(isf, 31, 32);
        if (sl == 0) { seld[n] = SKIPB; atomicAdd(&acc[3], totsum); }
    } else if (exc < k && ic >= k) {
        int cum = exc; float sa = exs; int d = -1; int rem = 0;
        for (int b = top; b > top - 64; --b) {
            int hb = (int)hn[b];
            if (cum + hb >= k) { d = b; rem = k - cum; break; }
            cum += hb; sa += sn[b];
        }
        atomicAdd(&acc[3], sa);
        if (d > 0) { seld[n] = (unsigned)d; selr[n] = rem; }
        else seld[n] = SKIPB;   // threshold in bin 0: values < 2^-100, negligible
    }
}

// ---------- positive-prior losses (no cross-block sync) ----------
extern "C" __global__ void __launch_bounds__(256) k_pos(
    const float* __restrict__ pred_boxes,
    const float* __restrict__ pred_cls,
    const float* __restrict__ pred_obj,
    const float* __restrict__ priors,
    const float* __restrict__ boxes,
    const int* __restrict__ labels,
    const unsigned int* __restrict__ plist,
    const unsigned int* __restrict__ flist,
    const int* __restrict__ cpart,
    const int* __restrict__ ecnt,
    float* __restrict__ acc)
{
    const int n = blockIdx.y;
    const int t = threadIdx.x;
    const int lane = t & 63;
    const int wave = t >> 6;

    __shared__ unsigned fl[MM];
    __shared__ int pref[MBLK + 2];
    __shared__ float sacc[3];

    if (t < MM) fl[t] = flist[n * MM + t];
    if (t < 3) sacc[t] = 0.f;
    if (t == 0) {
        int a = 0;
        for (int s = 0; s < MBLK; s++) { pref[s] = a; a += cpart[n * MBLK + s]; }
        pref[MBLK] = a;
        pref[MBLK + 1] = a + ecnt[n];
    }
    __syncthreads();
    const int T = pref[MBLK + 1];

    const unsigned* pl = plist + (size_t)n * PROW;
    float ce_s = 0.f, loc_s = 0.f, op_s = 0.f;
    for (int i = blockIdx.x * 4 + wave; i < T; i += POSX * 4) {
        int s = 0;
        while (pref[s + 1] <= i) s++;
        int slot = (s < MBLK) ? s * CHUNK + (i - pref[s])
                              : MBLK * CHUNK + (i - pref[MBLK]);
        const unsigned e = pl[slot];
        const int p = (int)(e & 0xFFFFu);
        int bm = (int)((e >> 16) & 31u);
#pragma unroll
        for (int j = 0; j < MM; j++)
            if (fl[j] == (unsigned)p) bm = j;           // ascending j = last-wins
        const size_t idx = (size_t)n * PP + p;

        const float* row = pred_cls + idx * NCLS;
        float a = row[lane];
        float b = (lane < NCLS - 64) ? row[lane + 64] : -INFINITY;
        float mx = fmaxf(a, b);
#pragma unroll
        for (int d = 1; d < 64; d <<= 1) mx = fmaxf(mx, __shfl_xor(mx, d));
        float se = expf(a - mx) + ((lane < NCLS - 64) ? expf(b - mx) : 0.f);
#pragma unroll
        for (int d = 1; d < 64; d <<= 1) se += __shfl_xor(se, d);

        if (lane == 0) {
            int lb = labels[n * MM + bm];
            ce_s += mx + logf(se) - row[lb];
        } else if (lane == 1) {
            float4 pb = *(const float4*)(priors + (size_t)p * 4);
            const float* bb = boxes + ((size_t)n * MM + bm) * 4;
            float gx1 = bb[0], gy1 = bb[1], gx2 = bb[2], gy2 = bb[3];
            float pcx = (pb.x + pb.z) * 0.5f, pcy = (pb.y + pb.w) * 0.5f;
            float pw = pb.z - pb.x, ph = pb.w - pb.y;
            float g0 = ((gx1 + gx2) * 0.5f - pcx) / (pw / 10.0f);
            float g1 = ((gy1 + gy2) * 0.5f - pcy) / (ph / 10.0f);
            float g2 = logf((gx2 - gx1) / pw) * 5.0f;
            float g3 = logf((gy2 - gy1) / ph) * 5.0f;
            float4 pd = *(const float4*)(pred_boxes + idx * 4);
            loc_s += sl1(pd.x - g0) + sl1(pd.y - g1) + sl1(pd.z - g2) + sl1(pd.w - g3);
        } else if (lane == 2) {
            float o = pred_obj[idx];
            op_s += (o - 1.0f) * (o - 1.0f);
        }
    }
    if (lane == 0 && ce_s != 0.f)  atomicAdd(&sacc[0], ce_s);
    if (lane == 1 && loc_s != 0.f) atomicAdd(&sacc[1], loc_s);
    if (lane == 2 && op_s != 0.f)  atomicAdd(&sacc[2], op_s);
    __syncthreads();
    if (t == 0) {
        if (sacc[0] != 0.f) atomicAdd(&acc[1], sacc[0]);
        if (sacc[1] != 0.f) atomicAdd(&acc[0], sacc[1]);
        if (sacc[2] != 0.f) atomicAdd(&acc[2], sacc[2]);
    }
}

// ---------- within-bin refine: one block per image, one PP scan ----------
extern "C" __global__ void __launch_bounds__(512) k_refine(
    const float* __restrict__ pred_obj,
    const unsigned int* __restrict__ posbit,
    const unsigned int* __restrict__ seld,
    const int* __restrict__ selr,
    float* __restrict__ acc)
{
    const int n = blockIdx.x;
    const unsigned dbin = seld[n];
    if (dbin == SKIPB) return;
    const int rem0 = selr[n];
    const int t = threadIdx.x;
    const int wave = t >> 6;

    __shared__ unsigned cand[CAPL];
    __shared__ int s_c;
    __shared__ unsigned rhist[128];
    __shared__ unsigned s_cur;
    __shared__ int s_rem;
    __shared__ float ws_[8], wc_[8];

    if (t == 0) s_c = 0;
    __syncthreads();

    const float* obj = pred_obj + (size_t)n * PP;
    const unsigned* pbits = posbit + n * PPW;
    for (int p = t; p < PP; p += 512) {
        unsigned msk = (pbits[p >> 5] >> (p & 31)) & 1u;
        float o = obj[p];
        float v = msk ? 0.f : o * o;
        unsigned bits = __float_as_uint(v);
        if ((bits >> BSH) == dbin) {
            int i = atomicAdd(&s_c, 1);
            if (i < CAPL) cand[i] = bits;
        }
    }
    __syncthreads();
    const int C = s_c;
    const bool lds_ok = (C <= CAPL);

    unsigned cur = dbin << BSH;
    int rem = rem0;
    for (int pass = 0; pass < 3; ++pass) {
        const int sh = 14 - 7 * pass;
        if (t < 128) rhist[t] = 0;
        __syncthreads();
        if (lds_ok) {
            for (int i = t; i < C; i += 512) {
                unsigned b = cand[i];
                if ((b >> (sh + 7)) == (cur >> (sh + 7)))
                    atomicAdd(&rhist[(b >> sh) & 127u], 1u);
            }
        } else {
            for (int p = t; p < PP; p += 512) {
                unsigned msk = (pbits[p >> 5] >> (p & 31)) & 1u;
                float o = obj[p];
                float v = msk ? 0.f : o * o;
                unsigned b = __float_as_uint(v);
                if ((b >> (sh + 7)) == (cur >> (sh + 7)))
                    atomicAdd(&rhist[(b >> sh) & 127u], 1u);
            }
        }
        __syncthreads();
        if (t == 0) {
            int cum = 0; int dd;
            for (dd = 127; dd > 0; --dd) {
                int h = (int)rhist[dd];
                if (cum + h >= rem) break;
                cum += h;
            }
            s_cur = cur | ((unsigned)dd << sh);
            s_rem = rem - cum;
        }
        __syncthreads();
        cur = s_cur; rem = s_rem;
        __syncthreads();
    }

    const unsigned thr = cur;
    const float thrv = __uint_as_float(thr);
    float ms = 0.f, mc = 0.f;
    if (lds_ok) {
        for (int i = t; i < C; i += 512) {
            unsigned b = cand[i];
            if (b > thr) { ms += __uint_as_float(b); mc += 1.f; }
        }
    } else {
        for (int p = t; p < PP; p += 512) {
            unsigned msk = (pbits[p >> 5] >> (p & 31)) & 1u;
            float o = obj[p];
            float v = msk ? 0.f : o * o;
            if (__float_as_uint(v) > thr) { ms += v; mc += 1.f; }
        }
    }
#pragma unroll
    for (int d = 32; d > 0; d >>= 1) {
        ms += __shfl_down(ms, d);
        mc += __shfl_down(mc, d);
    }
    if ((t & 63) == 0) { ws_[wave] = ms; wc_[wave] = mc; }
    __syncthreads();
    if (t == 0) {
        float ts = 0.f, tc = 0.f;
        for (int i = 0; i < 8; i++) { ts += ws_[i]; tc += wc_[i]; }
        atomicAdd(&acc[3], ts + ((float)rem0 - tc) * thrv);
    }
}

// ---------- finalize ----------
extern "C" __global__ void k_final(const float* __restrict__ acc,
                                   const int* __restrict__ pcnt,
                                   float* __restrict__ out)
{
    if (threadIdx.x == 0 && blockIdx.x == 0) {
        int np = 0, den = 0;
        for (int i = 0; i < NB; i++) {
            int c = pcnt[i];
            np += c;
            int k = c * 3; if (k > PP) k = PP;
            den += k;
        }
        float npf = (float)np;
        out[0] = acc[1] / npf + acc[2] / npf
               + acc[3] / fmaxf((float)den, 1.0f)
               + acc[0] / (npf * 4.0f);
    }
}

extern "C" void kernel_launch(void* const* d_in, const int* in_sizes, int n_in,
                              void* d_out, int out_size, void* d_ws, size_t ws_size,
                              hipStream_t stream) {
    const float* pred_boxes = (const float*)d_in[0];
    const float* pred_cls   = (const float*)d_in[1];
    const float* pred_obj   = (const float*)d_in[2];
    const float* priors     = (const float*)d_in[3];
    const float* boxes      = (const float*)d_in[4];
    const int*   labels     = (const int*)d_in[5];

    char* ws = (char*)d_ws;
    float* acc = (float*)(ws + WS_ACC);
    unsigned* seld = (unsigned*)(ws + WS_SELD);
    int* selr  = (int*)(ws + WS_SELR);
    int* pcnt  = (int*)(ws + WS_PCNT);
    int* ecnt  = (int*)(ws + WS_ECNT);
    int* cpart = (int*)(ws + WS_CPART);
    unsigned* flist = (unsigned*)(ws + WS_FLIST);
    unsigned long long* bkeyp = (unsigned long long*)(ws + WS_BKEYP);
    unsigned* posbit = (unsigned*)(ws + WS_POSBIT);
    unsigned* plist = (unsigned*)(ws + WS_PLIST);
    unsigned* hist = (unsigned*)(ws + WS_HIST);
    float* bsum = (float*)(ws + WS_BSUM);

    k_zero<<<128, 256, 0, stream>>>((unsigned*)d_ws);
    k_match<<<dim3(MBLK, NB), 256, 0, stream>>>(priors, boxes, pred_obj, bkeyp,
                                                posbit, plist, cpart, hist, bsum);
    k_force<<<1, 1024, 0, stream>>>(pred_obj, bkeyp, cpart, flist, posbit, plist,
                                    pcnt, ecnt, hist, bsum, seld, selr, acc);
    k_pos<<<dim3(POSX, NB), 256, 0, stream>>>(pred_boxes, pred_cls, pred_obj,
                                              priors, boxes, labels, plist, flist,
                                              cpart, ecnt, acc);
    k_refine<<<NB, 512, 0, stream>>>(pred_obj, posbit, seld, selr, acc);
    k_final<<<1, 64, 0, stream>>>(acc, pcnt, (float*)d_out);
}

// Round 8
// 192.521 us; speedup vs baseline: 3.2177x; 1.2514x over previous
//
#include <hip/hip_runtime.h>
#include <math.h>

#define NB 32
#define PP 24564
#define MM 32
#define NCLS 81
#define CHUNK 1024
#define MBLK 24          // ceil(PP/CHUNK)
#define PPW 768          // posbit u32 words per image
#define CEX 96           // k_ce blocks per image (96*4 waves*64 = 24576)
#define BSH 18           // bin = float_bits >> 18 (4096 bins; v in [0,1) -> bins < 4064)
#define HB 4096
#define CAPL 2048        // LDS candidate cap in k_sel

// ---- workspace layout (bytes); nothing pre-zeroed by host ----
#define WS_ACC    0        // float[4] (zeroed by k_force; acc[3] unused)
#define WS_PCNT   32       // int[NB] (k_force writes)
#define WS_CPART  288      // int[NB*MBLK] (k_match plain stores)
#define WS_FLIST  3456     // u32[NB*MM]
#define WS_BKEYP  8192     // u64[NB*MBLK*MM]
#define WS_POSBIT 204800   // u32[NB*PPW] (k_match fully rewrites)
#define WS_M8     303104   // u8[NB*PP] natural match byte
#define WS_VAL    1089152  // float[NB*PP] masked neg value o^2 (16B aligned)
#define WS_HN     4233344  // float[NB] per-image hardneg sums (k_sel plain stores)

__device__ __forceinline__ float sl1(float d) {
    float a = fabsf(d);
    return a < 1.0f ? 0.5f * d * d : a - 0.5f;
}
__device__ __forceinline__ unsigned long long u64max(unsigned long long a, unsigned long long b) {
    return a > b ? a : b;
}

// ---------- matching: per-prior + per-object argmax; emits posbit, m8, val ----------
extern "C" __global__ void __launch_bounds__(256) k_match(
    const float* __restrict__ priors,
    const float* __restrict__ boxes,
    const float* __restrict__ obj,
    unsigned long long* __restrict__ bkeyp,
    unsigned int* __restrict__ posbit,
    unsigned char* __restrict__ m8,
    float* __restrict__ val,
    int* __restrict__ cpart)
{
    const int n = blockIdx.y;
    const int t = threadIdx.x;
    const int lane = t & 63;
    const int wave = t >> 6;
    const int bx = blockIdx.x;
    const int p0 = bx * CHUNK;

    __shared__ float4 spri[CHUNK];
    __shared__ float bx0[MM], by0[MM], bx1[MM], by1[MM], bar_[MM];
    __shared__ unsigned long long wk[4][MM];
    __shared__ int bcnt;

    float ov[4];
#pragma unroll
    for (int i = 0; i < 4; i++) {
        int p = p0 + t + i * 256;
        float4 v;
        if (p < PP) { v = *(const float4*)(priors + (size_t)p * 4);
                      ov[i] = obj[(size_t)n * PP + p]; }
        else { v.x = 3.f; v.y = 3.f; v.z = 3.5f; v.w = 3.5f; ov[i] = 0.f; }
        spri[t + i * 256] = v;
    }
    if (t < MM) {
        const float* b = boxes + ((size_t)n * MM + t) * 4;
        float x1 = b[0], y1 = b[1], x2 = b[2], y2 = b[3];
        bx0[t] = x1; by0[t] = y1; bx1[t] = x2; by1[t] = y2;
        bar_[t] = (x2 - x1) * (y2 - y1);
    }
    if (t == 0) bcnt = 0;
    __syncthreads();

    float4 pr0 = spri[t], pr1 = spri[t + 256], pr2 = spri[t + 512], pr3 = spri[t + 768];
    const float pa0 = (pr0.z - pr0.x) * (pr0.w - pr0.y);
    const float pa1 = (pr1.z - pr1.x) * (pr1.w - pr1.y);
    const float pa2 = (pr2.z - pr2.x) * (pr2.w - pr2.y);
    const float pa3 = (pr3.z - pr3.x) * (pr3.w - pr3.y);
    unsigned pb0 = 0, pb1 = 0, pb2 = 0, pb3 = 0;   // per-prior keys: trunc-iou | (31-m)

#define DO_IOU(PR, PA, PB, ROFF) { \
        float w = fminf(x1, PR.z) - fmaxf(x0, PR.x); \
        float h = fminf(y1, PR.w) - fmaxf(y0, PR.y); \
        w = fmaxf(w, 0.0f); h = fmaxf(h, 0.0f); \
        float inter = w * h; \
        float iou = inter / (ar + PA - inter); \
        unsigned ib = __float_as_uint(iou); \
        unsigned nk = (ib & 0xFFFFFFE0u) | (unsigned)(31 - m); \
        PB = PB > nk ? PB : nk; \
        unsigned long long kk = ((unsigned long long)ib << 32) \
            | (unsigned long long)(0xFFFFFFFFu - (unsigned)(p0 + t + (ROFF))); \
        km = u64max(km, kk); }

#pragma unroll 2
    for (int m = 0; m < MM; m++) {
        const float x0 = bx0[m], y0 = by0[m], x1 = bx1[m], y1 = by1[m], ar = bar_[m];
        unsigned long long km = 0ULL;
        DO_IOU(pr0, pa0, pb0, 0)
        DO_IOU(pr1, pa1, pb1, 256)
        DO_IOU(pr2, pa2, pb2, 512)
        DO_IOU(pr3, pa3, pb3, 768)
#pragma unroll
        for (int d = 1; d < 64; d <<= 1)
            km = u64max(km, (unsigned long long)__shfl_xor(km, d));
        if (lane == 0) wk[wave][m] = km;
    }
#undef DO_IOU

    int cnt = 0;
#define ROWOUT(PB, R) { \
        int p = p0 + t + (R) * 256; \
        bool pos = (PB >= 0x3F000000u) && (p < PP); \
        unsigned long long ball = __ballot(pos); \
        if (lane == 0) { \
            int wi = n * PPW + ((p0 + (R) * 256 + wave * 64) >> 5); \
            posbit[wi] = (unsigned)ball; posbit[wi + 1] = (unsigned)(ball >> 32); \
            cnt += __popcll(ball); \
        } \
        if (p < PP) { \
            size_t idx = (size_t)n * PP + p; \
            m8[idx] = (unsigned char)(31u - (PB & 31u)); \
            val[idx] = pos ? 0.f : ov[R] * ov[R]; \
        } }
    ROWOUT(pb0, 0) ROWOUT(pb1, 1) ROWOUT(pb2, 2) ROWOUT(pb3, 3)
#undef ROWOUT
    if (lane == 0 && cnt) atomicAdd(&bcnt, cnt);

    __syncthreads();
    if (t == 0) cpart[n * MBLK + bx] = bcnt;
    if (t < MM) {
        unsigned long long r = u64max(u64max(wk[0][t], wk[1][t]),
                                      u64max(wk[2][t], wk[3][t]));
        bkeyp[((size_t)n * MBLK + bx) * MM + t] = r;
    }
}

// ---------- forced overrides + totals + acc zero (1 block) ----------
extern "C" __global__ void __launch_bounds__(1024) k_force(
    const unsigned long long* __restrict__ bkeyp,
    const int* __restrict__ cpart,
    unsigned int* __restrict__ flist,
    unsigned int* __restrict__ posbit,
    float* __restrict__ val,
    int* __restrict__ pcnt,
    float* __restrict__ acc)
{
    const int t = threadIdx.x;          // 1024 = NB*MM
    __shared__ int lecnt[NB];
    if (t < NB) lecnt[t] = 0;
    if (t < 4) acc[t] = 0.f;
    __syncthreads();

    const int n = t >> 5, m = t & 31;
    const unsigned long long* bp = bkeyp + (size_t)n * MBLK * MM + m;
    unsigned long long r = 0ULL;
#pragma unroll
    for (int s = 0; s < MBLK; s++) r = u64max(r, bp[(size_t)s * MM]);
    unsigned p = 0xFFFFFFFFu - (unsigned)(r & 0xFFFFFFFFULL);
    flist[t] = p;
    unsigned bit = 1u << (p & 31);
    unsigned old = atomicOr(&posbit[n * PPW + (p >> 5)], bit);
    if (!(old & bit)) {                 // newly positive: count + mask its value
        atomicAdd(&lecnt[n], 1);
        val[(size_t)n * PP + p] = 0.f;
    }
    __syncthreads();
    if (t < NB) {
        int tot = lecnt[t];
        for (int b = 0; b < MBLK; b++) tot += cpart[t * MBLK + b];
        pcnt[t] = tot;
    }
}

// ---------- positive losses: bitmap scan, 2 positives per wave ----------
extern "C" __global__ void __launch_bounds__(256) k_ce(
    const float* __restrict__ pred_boxes,
    const float* __restrict__ pred_cls,
    const float* __restrict__ pred_obj,
    const float* __restrict__ priors,
    const float* __restrict__ boxes,
    const int* __restrict__ labels,
    const unsigned char* __restrict__ m8,
    const unsigned int* __restrict__ posbit,
    const unsigned int* __restrict__ flist,
    float* __restrict__ acc)
{
    const int n = blockIdx.y;
    const int t = threadIdx.x;
    const int lane = t & 63;
    const int wave = t >> 6;
    const int half = lane >> 5;
    const int hl = lane & 31;

    __shared__ unsigned fl[MM];
    __shared__ float sacc[3];
    if (t < MM) fl[t] = flist[n * MM + t];
    if (t < 3) sacc[t] = 0.f;
    __syncthreads();

    const int base = (blockIdx.x * 4 + wave) * 64;
    const int w0 = n * PPW + (base >> 5);
    unsigned long long mask = (unsigned long long)posbit[w0]
                            | ((unsigned long long)posbit[w0 + 1] << 32);

    float ce_s = 0.f, loc_s = 0.f, op_s = 0.f;
    while (mask) {
        int i1 = __ffsll((long long)mask) - 1; mask &= mask - 1;
        int i2 = -1;
        if (mask) { i2 = __ffsll((long long)mask) - 1; mask &= mask - 1; }
        const int pi = half ? i2 : i1;
        const bool act = pi >= 0;
        const int p = base + (act ? pi : 0);
        const size_t idx = (size_t)n * PP + p;

        int bm = act ? (int)m8[idx] : 0;
#pragma unroll
        for (int j = 0; j < MM; j++)
            if (fl[j] == (unsigned)p) bm = j;      // ascending j = last-wins

        const float* row = pred_cls + idx * NCLS;
        float a = act ? row[hl] : -INFINITY;
        float b = act ? row[hl + 32] : -INFINITY;
        float c = (act && hl + 64 < NCLS) ? row[hl + 64] : -INFINITY;
        float mx = fmaxf(fmaxf(a, b), c);
#pragma unroll
        for (int d = 1; d < 32; d <<= 1) mx = fmaxf(mx, __shfl_xor(mx, d));
        float se = act ? (expf(a - mx) + expf(b - mx)
                          + ((hl + 64 < NCLS) ? expf(c - mx) : 0.f)) : 0.f;
#pragma unroll
        for (int d = 1; d < 32; d <<= 1) se += __shfl_xor(se, d);

        if (act) {
            if (hl == 0) {
                int lb = labels[n * MM + bm];
                ce_s += mx + logf(se) - row[lb];
            } else if (hl == 1) {
                float4 pb = *(const float4*)(priors + (size_t)p * 4);
                const float* bb = boxes + ((size_t)n * MM + bm) * 4;
                float gx1 = bb[0], gy1 = bb[1], gx2 = bb[2], gy2 = bb[3];
                float pcx = (pb.x + pb.z) * 0.5f, pcy = (pb.y + pb.w) * 0.5f;
                float pw = pb.z - pb.x, ph = pb.w - pb.y;
                float g0 = ((gx1 + gx2) * 0.5f - pcx) / (pw / 10.0f);
                float g1 = ((gy1 + gy2) * 0.5f - pcy) / (ph / 10.0f);
                float g2 = logf((gx2 - gx1) / pw) * 5.0f;
                float g3 = logf((gy2 - gy1) / ph) * 5.0f;
                float4 pd = *(const float4*)(pred_boxes + idx * 4);
                loc_s += sl1(pd.x - g0) + sl1(pd.y - g1)
                       + sl1(pd.z - g2) + sl1(pd.w - g3);
            } else if (hl == 2) {
                float o = pred_obj[idx];
                op_s += (o - 1.0f) * (o - 1.0f);
            }
        }
    }
    if (ce_s != 0.f)  atomicAdd(&sacc[0], ce_s);
    if (loc_s != 0.f) atomicAdd(&sacc[1], loc_s);
    if (op_s != 0.f)  atomicAdd(&sacc[2], op_s);
    __syncthreads();
    if (t == 0) {
        if (sacc[0] != 0.f) atomicAdd(&acc[1], sacc[0]);
        if (sacc[1] != 0.f) atomicAdd(&acc[0], sacc[1]);
        if (sacc[2] != 0.f) atomicAdd(&acc[2], sacc[2]);
    }
}

// ---------- exact top-k sum per image from val[] (self-contained) ----------
extern "C" __global__ void __launch_bounds__(512) k_sel(
    const float* __restrict__ val,
    const int* __restrict__ pcnt,
    float* __restrict__ hn)
{
    const int n = blockIdx.x;
    const int t = threadIdx.x;
    const int wave = t >> 6;
    int k = pcnt[n] * 3; if (k > PP) k = PP;
    const float* v = val + (size_t)n * PP;
    const float4* v4 = (const float4*)v;
    const int N4 = PP / 4;   // 6141

    __shared__ float wred[8], wred2[8];

    if (k <= 0) { if (t == 0) hn[n] = 0.f; return; }

    if (k >= PP) {           // hmask covers everything: sum all
        float s = 0.f;
        for (int i = t; i < N4; i += 512) {
            float4 q = v4[i]; s += q.x + q.y + q.z + q.w;
        }
#pragma unroll
        for (int d = 32; d > 0; d >>= 1) s += __shfl_down(s, d);
        if ((t & 63) == 0) wred[wave] = s;
        __syncthreads();
        if (t == 0) { float r = 0; for (int i = 0; i < 8; i++) r += wred[i]; hn[n] = r; }
        return;
    }

    __shared__ unsigned hist[HB];
    __shared__ unsigned ssc[512];
    __shared__ unsigned cand[CAPL];
    __shared__ int s_c, s_d, s_rem;
    __shared__ unsigned s_cur;
    __shared__ int s_rr;
    __shared__ unsigned rh[128];

    for (int i = t; i < HB; i += 512) hist[i] = 0;
    if (t == 0) s_c = 0;
    __syncthreads();

    for (int i = t; i < N4; i += 512) {
        float4 q = v4[i];
        atomicAdd(&hist[__float_as_uint(q.x) >> BSH], 1u);
        atomicAdd(&hist[__float_as_uint(q.y) >> BSH], 1u);
        atomicAdd(&hist[__float_as_uint(q.z) >> BSH], 1u);
        atomicAdd(&hist[__float_as_uint(q.w) >> BSH], 1u);
    }
    __syncthreads();

    // chunked descending prefix: thread t owns bins [4095-8t-7 .. 4095-8t]
    unsigned csum = 0;
#pragma unroll
    for (int j = 0; j < 8; j++) csum += hist[4095 - 8 * t - j];
    ssc[t] = csum; __syncthreads();
    for (int off = 1; off < 512; off <<= 1) {
        unsigned x = (t >= off) ? ssc[t - off] : 0u;
        __syncthreads(); ssc[t] += x; __syncthreads();
    }
    unsigned incl = ssc[t], excl = incl - csum;
    if (excl < (unsigned)k && incl >= (unsigned)k) {
        unsigned cum = excl;
#pragma unroll
        for (int j = 0; j < 8; j++) {
            int b = 4095 - 8 * t - j; unsigned h = hist[b];
            if (cum + h >= (unsigned)k) { s_d = b; s_rem = (int)((unsigned)k - cum); break; }
            cum += h;
        }
    }
    __syncthreads();
    const int d = s_d; const int rem0 = s_rem;

    // scan2: exact sum of bins>d, collect bin-d candidates
    float ms = 0.f;
    for (int i = t; i < N4; i += 512) {
        float4 q = v4[i];
#define HND(C) { unsigned b = __float_as_uint(C); int bn = (int)(b >> BSH); \
        if (bn > d) ms += (C); \
        else if (bn == d) { int ix = atomicAdd(&s_c, 1); if (ix < CAPL) cand[ix] = b; } }
        HND(q.x) HND(q.y) HND(q.z) HND(q.w)
#undef HND
    }
    __syncthreads();
    const int C = s_c;
    const bool ok = (C <= CAPL);

    // refine within bin d: 3 LDS-radix passes fix bits [17:0] exactly
    unsigned cur = (unsigned)d << BSH; int rem = rem0;
    const int shs[3] = {11, 4, 0};
    const int wbs[3] = {7, 7, 4};
    for (int ps = 0; ps < 3; ps++) {
        const int sh = shs[ps], wb = wbs[ps], W = 1 << wb;
        if (t < W) rh[t] = 0;
        __syncthreads();
        if (ok) {
            for (int i = t; i < C; i += 512) {
                unsigned b = cand[i];
                if ((b >> (sh + wb)) == (cur >> (sh + wb)))
                    atomicAdd(&rh[(b >> sh) & (W - 1)], 1u);
            }
        } else {
            for (int i = t; i < PP; i += 512) {
                unsigned b = __float_as_uint(v[i]);
                if ((b >> (sh + wb)) == (cur >> (sh + wb)))
                    atomicAdd(&rh[(b >> sh) & (W - 1)], 1u);
            }
        }
        __syncthreads();
        if (t == 0) {
            unsigned cum = 0; int dd;
            for (dd = W - 1; dd > 0; --dd) {
                unsigned h = rh[dd];
                if (cum + h >= (unsigned)rem) break;
                cum += h;
            }
            s_cur = cur | ((unsigned)dd << sh);
            s_rr = rem - (int)cum;
        }
        __syncthreads();
        cur = s_cur; rem = s_rr;
        __syncthreads();
    }
    const unsigned thr = cur;
    const float thrv = __uint_as_float(thr);

    float sg = ms, cg = 0.f;
    if (ok) {
        for (int i = t; i < C; i += 512) {
            unsigned b = cand[i];
            if (b > thr) { sg += __uint_as_float(b); cg += 1.f; }
        }
    } else {
        for (int i = t; i < PP; i += 512) {
            unsigned b = __float_as_uint(v[i]);
            if ((int)(b >> BSH) == d && b > thr) { sg += __uint_as_float(b); cg += 1.f; }
        }
    }
#pragma unroll
    for (int dd = 32; dd > 0; dd >>= 1) {
        sg += __shfl_down(sg, dd);
        cg += __shfl_down(cg, dd);
    }
    if ((t & 63) == 0) { wred[wave] = sg; wred2[wave] = cg; }
    __syncthreads();
    if (t == 0) {
        float S = 0.f, Cc = 0.f;
        for (int i = 0; i < 8; i++) { S += wred[i]; Cc += wred2[i]; }
        hn[n] = S + ((float)rem0 - Cc) * thrv;
    }
}

// ---------- finalize ----------
extern "C" __global__ void k_final(const float* __restrict__ acc,
                                   const int* __restrict__ pcnt,
                                   const float* __restrict__ hn,
                                   float* __restrict__ out)
{
    if (threadIdx.x == 0 && blockIdx.x == 0) {
        int np = 0, den = 0;
        float hs = 0.f;
        for (int i = 0; i < NB; i++) {
            int c = pcnt[i];
            np += c;
            int k = c * 3; if (k > PP) k = PP;
            den += k;
            hs += hn[i];
        }
        float npf = (float)np;
        out[0] = acc[1] / npf + acc[2] / npf
               + hs / fmaxf((float)den, 1.0f)
               + acc[0] / (npf * 4.0f);
    }
}

extern "C" void kernel_launch(void* const* d_in, const int* in_sizes, int n_in,
                              void* d_out, int out_size, void* d_ws, size_t ws_size,
                              hipStream_t stream) {
    const float* pred_boxes = (const float*)d_in[0];
    const float* pred_cls   = (const float*)d_in[1];
    const float* pred_obj   = (const float*)d_in[2];
    const float* priors     = (const float*)d_in[3];
    const float* boxes      = (const float*)d_in[4];
    const int*   labels     = (const int*)d_in[5];

    char* ws = (char*)d_ws;
    float* acc = (float*)(ws + WS_ACC);
    int* pcnt  = (int*)(ws + WS_PCNT);
    int* cpart = (int*)(ws + WS_CPART);
    unsigned* flist = (unsigned*)(ws + WS_FLIST);
    unsigned long long* bkeyp = (unsigned long long*)(ws + WS_BKEYP);
    unsigned* posbit = (unsigned*)(ws + WS_POSBIT);
    unsigned char* m8 = (unsigned char*)(ws + WS_M8);
    float* val = (float*)(ws + WS_VAL);
    float* hn  = (float*)(ws + WS_HN);

    k_match<<<dim3(MBLK, NB), 256, 0, stream>>>(priors, boxes, pred_obj, bkeyp,
                                                posbit, m8, val, cpart);
    k_force<<<1, 1024, 0, stream>>>(bkeyp, cpart, flist, posbit, val, pcnt, acc);
    k_ce<<<dim3(CEX, NB), 256, 0, stream>>>(pred_boxes, pred_cls, pred_obj,
                                            priors, boxes, labels, m8, posbit,
                                            flist, acc);
    k_sel<<<NB, 512, 0, stream>>>(val, pcnt, hn);
    k_final<<<1, 64, 0, stream>>>(acc, pcnt, hn, (float*)d_out);
}

// Round 9
// 100.617 us; speedup vs baseline: 6.1567x; 1.9134x over previous
//
#include <hip/hip_runtime.h>
#include <math.h>

#define NB 32
#define PP 24564
#define MM 32
#define NCLS 81
#define CHUNK 1024
#define MBLK 24          // ceil(PP/CHUNK)
#define PPW 768          // posbit u32 words per image
#define CEX 24           // k_ce blocks per image (24 * 16 waves * 64 = 24576)
#define BSH 18           // bin = float_bits >> 18 (4096 bins)
#define HB 4096
#define CAPL 2048        // LDS candidate cap in k_sel

// ---- workspace layout (bytes); nothing pre-zeroed by host ----
#define WS_ACC    0        // float[4] (zeroed by k_match block 0)
#define WS_DONE   16       // int (zeroed by k_match block 0)
#define WS_PCNT   32       // int[NB] (k_sel writes)
#define WS_HN     160      // float[NB] (k_sel writes)
#define WS_CPART  288      // int[NB*MBLK] (k_match plain stores)
#define WS_BKEYP  3584     // u64[NB*MBLK*MM]
#define WS_POSBIT 200192   // u32[NB*PPW] (k_match fully rewrites; natural bits only)
#define WS_M8     298496   // u8[NB*PP]
#define WS_VAL    1084544  // float[NB*PP] masked neg value o^2 (16B aligned)

__device__ __forceinline__ float sl1(float d) {
    float a = fabsf(d);
    return a < 1.0f ? 0.5f * d * d : a - 0.5f;
}
__device__ __forceinline__ unsigned long long u64max(unsigned long long a, unsigned long long b) {
    return a > b ? a : b;
}

// ---------- matching: per-prior + per-object argmax; emits posbit, m8, val ----------
extern "C" __global__ void __launch_bounds__(256) k_match(
    const float* __restrict__ priors,
    const float* __restrict__ boxes,
    const float* __restrict__ obj,
    unsigned long long* __restrict__ bkeyp,
    unsigned int* __restrict__ posbit,
    unsigned char* __restrict__ m8,
    float* __restrict__ val,
    int* __restrict__ cpart,
    float* __restrict__ acc,
    int* __restrict__ done)
{
    const int n = blockIdx.y;
    const int t = threadIdx.x;
    const int lane = t & 63;
    const int wave = t >> 6;
    const int bx = blockIdx.x;
    const int p0 = bx * CHUNK;

    if (bx == 0 && n == 0) {            // re-arm accumulators each call
        if (t < 4) acc[t] = 0.f;
        if (t == 4) *done = 0;
    }

    __shared__ float4 spri[CHUNK];
    __shared__ float bx0[MM], by0[MM], bx1[MM], by1[MM], bar_[MM];
    __shared__ unsigned long long wk[4][MM];
    __shared__ int bcnt;

    float ov[4];
#pragma unroll
    for (int i = 0; i < 4; i++) {
        int p = p0 + t + i * 256;
        float4 v;
        if (p < PP) { v = *(const float4*)(priors + (size_t)p * 4);
                      ov[i] = obj[(size_t)n * PP + p]; }
        else { v.x = 3.f; v.y = 3.f; v.z = 3.5f; v.w = 3.5f; ov[i] = 0.f; }
        spri[t + i * 256] = v;
    }
    if (t < MM) {
        const float* b = boxes + ((size_t)n * MM + t) * 4;
        float x1 = b[0], y1 = b[1], x2 = b[2], y2 = b[3];
        bx0[t] = x1; by0[t] = y1; bx1[t] = x2; by1[t] = y2;
        bar_[t] = (x2 - x1) * (y2 - y1);
    }
    if (t == 0) bcnt = 0;
    __syncthreads();

    float4 pr0 = spri[t], pr1 = spri[t + 256], pr2 = spri[t + 512], pr3 = spri[t + 768];
    const float pa0 = (pr0.z - pr0.x) * (pr0.w - pr0.y);
    const float pa1 = (pr1.z - pr1.x) * (pr1.w - pr1.y);
    const float pa2 = (pr2.z - pr2.x) * (pr2.w - pr2.y);
    const float pa3 = (pr3.z - pr3.x) * (pr3.w - pr3.y);
    unsigned pb0 = 0, pb1 = 0, pb2 = 0, pb3 = 0;   // per-prior keys: trunc-iou | (31-m)

#define DO_IOU(PR, PA, PB, ROFF) { \
        float w = fminf(x1, PR.z) - fmaxf(x0, PR.x); \
        float h = fminf(y1, PR.w) - fmaxf(y0, PR.y); \
        w = fmaxf(w, 0.0f); h = fmaxf(h, 0.0f); \
        float inter = w * h; \
        float iou = inter / (ar + PA - inter); \
        unsigned ib = __float_as_uint(iou); \
        unsigned nk = (ib & 0xFFFFFFE0u) | (unsigned)(31 - m); \
        PB = PB > nk ? PB : nk; \
        unsigned long long kk = ((unsigned long long)ib << 32) \
            | (unsigned long long)(0xFFFFFFFFu - (unsigned)(p0 + t + (ROFF))); \
        km = u64max(km, kk); }

#pragma unroll 2
    for (int m = 0; m < MM; m++) {
        const float x0 = bx0[m], y0 = by0[m], x1 = bx1[m], y1 = by1[m], ar = bar_[m];
        unsigned long long km = 0ULL;
        DO_IOU(pr0, pa0, pb0, 0)
        DO_IOU(pr1, pa1, pb1, 256)
        DO_IOU(pr2, pa2, pb2, 512)
        DO_IOU(pr3, pa3, pb3, 768)
#pragma unroll
        for (int d = 1; d < 64; d <<= 1)
            km = u64max(km, (unsigned long long)__shfl_xor(km, d));
        if (lane == 0) wk[wave][m] = km;
    }
#undef DO_IOU

    int cnt = 0;
#define ROWOUT(PB, R) { \
        int p = p0 + t + (R) * 256; \
        bool pos = (PB >= 0x3F000000u) && (p < PP); \
        unsigned long long ball = __ballot(pos); \
        if (lane == 0) { \
            int wi = n * PPW + ((p0 + (R) * 256 + wave * 64) >> 5); \
            posbit[wi] = (unsigned)ball; posbit[wi + 1] = (unsigned)(ball >> 32); \
            cnt += __popcll(ball); \
        } \
        if (p < PP) { \
            size_t idx = (size_t)n * PP + p; \
            m8[idx] = (unsigned char)(31u - (PB & 31u)); \
            val[idx] = pos ? 0.f : ov[R] * ov[R]; \
        } }
    ROWOUT(pb0, 0) ROWOUT(pb1, 1) ROWOUT(pb2, 2) ROWOUT(pb3, 3)
#undef ROWOUT
    if (lane == 0 && cnt) atomicAdd(&bcnt, cnt);

    __syncthreads();
    if (t == 0) cpart[n * MBLK + bx] = bcnt;
    if (t < MM) {
        unsigned long long r = u64max(u64max(wk[0][t], wk[1][t]),
                                      u64max(wk[2][t], wk[3][t]));
        bkeyp[((size_t)n * MBLK + bx) * MM + t] = r;
    }
}

// ---------- positive losses: in-block forced resolve, bitmap scan, 2/wave ----------
extern "C" __global__ void __launch_bounds__(1024) k_ce(
    const float* __restrict__ pred_boxes,
    const float* __restrict__ pred_cls,
    const float* __restrict__ pred_obj,
    const float* __restrict__ priors,
    const float* __restrict__ boxes,
    const int* __restrict__ labels,
    const unsigned char* __restrict__ m8,
    const unsigned int* __restrict__ posbit,
    const unsigned long long* __restrict__ bkeyp,
    float* __restrict__ acc)
{
    const int n = blockIdx.y;
    const int t = threadIdx.x;
    const int lane = t & 63;
    const int wave = t >> 6;          // 0..15
    const int half = lane >> 5;
    const int hl = lane & 31;
    const int blockbase = blockIdx.x * 1024;

    __shared__ unsigned fl[MM];
    __shared__ unsigned long long fm[16];
    __shared__ float sacc[3];
    if (t < 16) fm[t] = 0ULL;
    if (t < 3) sacc[t] = 0.f;
    __syncthreads();
    if (t < MM) {                     // recompute forced prior per object
        const unsigned long long* bp = bkeyp + (size_t)n * MBLK * MM + t;
        unsigned long long r = 0ULL;
#pragma unroll
        for (int s = 0; s < MBLK; s++) r = u64max(r, bp[(size_t)s * MM]);
        unsigned p = ~(unsigned)(r & 0xFFFFFFFFULL);
        fl[t] = p;
        int rel = (int)p - blockbase;
        if (rel >= 0 && rel < 1024)   // force-positive inside this block's range
            atomicOr(&fm[rel >> 6], 1ULL << (rel & 63));
    }
    __syncthreads();

    const int base = blockbase + wave * 64;
    const int w0 = n * PPW + (base >> 5);
    unsigned long long mask = ((unsigned long long)posbit[w0]
                            | ((unsigned long long)posbit[w0 + 1] << 32))
                            | fm[wave];

    float ce_s = 0.f, loc_s = 0.f, op_s = 0.f;
    while (mask) {
        int i1 = __ffsll((long long)mask) - 1; mask &= mask - 1;
        int i2 = -1;
        if (mask) { i2 = __ffsll((long long)mask) - 1; mask &= mask - 1; }
        const int pi = half ? i2 : i1;
        const bool act = pi >= 0;
        const int p = base + (act ? pi : 0);
        const size_t idx = (size_t)n * PP + p;

        int bm = act ? (int)m8[idx] : 0;
#pragma unroll
        for (int j = 0; j < MM; j++)
            if (fl[j] == (unsigned)p) bm = j;      // ascending j = last-wins

        const float* row = pred_cls + idx * NCLS;
        float a = act ? row[hl] : -INFINITY;
        float b = act ? row[hl + 32] : -INFINITY;
        float c = (act && hl + 64 < NCLS) ? row[hl + 64] : -INFINITY;
        float mx = fmaxf(fmaxf(a, b), c);
#pragma unroll
        for (int d = 1; d < 32; d <<= 1) mx = fmaxf(mx, __shfl_xor(mx, d));
        float se = act ? (expf(a - mx) + expf(b - mx)
                          + ((hl + 64 < NCLS) ? expf(c - mx) : 0.f)) : 0.f;
#pragma unroll
        for (int d = 1; d < 32; d <<= 1) se += __shfl_xor(se, d);

        if (act) {
            if (hl == 0) {
                int lb = labels[n * MM + bm];
                ce_s += mx + logf(se) - row[lb];
            } else if (hl == 1) {
                float4 pb = *(const float4*)(priors + (size_t)p * 4);
                const float* bb = boxes + ((size_t)n * MM + bm) * 4;
                float gx1 = bb[0], gy1 = bb[1], gx2 = bb[2], gy2 = bb[3];
                float pcx = (pb.x + pb.z) * 0.5f, pcy = (pb.y + pb.w) * 0.5f;
                float pw = pb.z - pb.x, ph = pb.w - pb.y;
                float g0 = ((gx1 + gx2) * 0.5f - pcx) / (pw / 10.0f);
                float g1 = ((gy1 + gy2) * 0.5f - pcy) / (ph / 10.0f);
                float g2 = logf((gx2 - gx1) / pw) * 5.0f;
                float g3 = logf((gy2 - gy1) / ph) * 5.0f;
                float4 pd = *(const float4*)(pred_boxes + idx * 4);
                loc_s += sl1(pd.x - g0) + sl1(pd.y - g1)
                       + sl1(pd.z - g2) + sl1(pd.w - g3);
            } else if (hl == 2) {
                float o = pred_obj[idx];
                op_s += (o - 1.0f) * (o - 1.0f);
            }
        }
    }
    if (ce_s != 0.f)  atomicAdd(&sacc[0], ce_s);
    if (loc_s != 0.f) atomicAdd(&sacc[1], loc_s);
    if (op_s != 0.f)  atomicAdd(&sacc[2], op_s);
    __syncthreads();
    if (t == 0) {                     // fire-and-forget, 3 per block
        if (sacc[0] != 0.f) atomicAdd(&acc[1], sacc[0]);
        if (sacc[1] != 0.f) atomicAdd(&acc[0], sacc[1]);
        if (sacc[2] != 0.f) atomicAdd(&acc[2], sacc[2]);
    }
}

// ---------- exact top-k sum + finalize (32 blocks, last-block completes) ----------
extern "C" __global__ void __launch_bounds__(512) k_sel(
    const unsigned long long* __restrict__ bkeyp,
    const unsigned int* __restrict__ posbit,
    const int* __restrict__ cpart,
    float* __restrict__ val,
    int* __restrict__ pcnt,
    float* __restrict__ hn,
    const float* __restrict__ acc,
    int* __restrict__ done,
    float* __restrict__ out)
{
    const int n = blockIdx.x;
    const int t = threadIdx.x;
    const int wave = t >> 6;
    float* v = val + (size_t)n * PP;
    const float4* v4 = (const float4*)v;
    const int N4 = PP / 4;   // 6141

    __shared__ unsigned fl[MM];
    __shared__ int scp[MBLK];
    __shared__ int s_extras, s_tot;
    __shared__ float wred[8], wred2[8];

    // forced priors: recompute, dedupe (largest-m canonical), zero val at new positives
    unsigned myp = 0; bool newpos = false;
    if (t < MM) {
        const unsigned long long* bp = bkeyp + (size_t)n * MBLK * MM + t;
        unsigned long long r = 0ULL;
#pragma unroll
        for (int s = 0; s < MBLK; s++) r = u64max(r, bp[(size_t)s * MM]);
        myp = ~(unsigned)(r & 0xFFFFFFFFULL);
        fl[t] = myp;
    }
    if (t < MBLK) scp[t] = cpart[n * MBLK + t];
    __syncthreads();
    if (t < MM) {
        bool uniq = true;
        for (int j = t + 1; j < MM; j++) if (fl[j] == myp) uniq = false;
        unsigned bitw = posbit[n * PPW + (myp >> 5)];
        newpos = uniq && !((bitw >> (myp & 31)) & 1u);
        if (newpos) v[myp] = 0.f;     // mask forced-new positive
        unsigned long long bal = __ballot(newpos);
        if (t == 0) s_extras = __popcll(bal);
    }
    __syncthreads();
    if (t == 0) {
        int tot = s_extras;
        for (int i = 0; i < MBLK; i++) tot += scp[i];
        s_tot = tot;
        pcnt[n] = tot;
    }
    __syncthreads();
    int k = s_tot * 3; if (k > PP) k = PP;

    float result = 0.f;
    if (k >= PP) {                    // hmask covers everything: sum all
        float s = 0.f;
        for (int i = t; i < N4; i += 512) {
            float4 q = v4[i]; s += q.x + q.y + q.z + q.w;
        }
#pragma unroll
        for (int d = 32; d > 0; d >>= 1) s += __shfl_down(s, d);
        if ((t & 63) == 0) wred[wave] = s;
        __syncthreads();
        if (t == 0) { for (int i = 0; i < 8; i++) result += wred[i]; }
    } else if (k > 0) {
        __shared__ unsigned hist[HB];
        __shared__ unsigned ssc[512];
        __shared__ unsigned cand[CAPL];
        __shared__ int s_c, s_d, s_rem;
        __shared__ unsigned s_cur;
        __shared__ int s_rr;
        __shared__ unsigned rh[128];

        for (int i = t; i < HB; i += 512) hist[i] = 0;
        if (t == 0) s_c = 0;
        __syncthreads();

        for (int i = t; i < N4; i += 512) {
            float4 q = v4[i];
            atomicAdd(&hist[__float_as_uint(q.x) >> BSH], 1u);
            atomicAdd(&hist[__float_as_uint(q.y) >> BSH], 1u);
            atomicAdd(&hist[__float_as_uint(q.z) >> BSH], 1u);
            atomicAdd(&hist[__float_as_uint(q.w) >> BSH], 1u);
        }
        __syncthreads();

        // chunked descending prefix: thread t owns bins [4095-8t-7 .. 4095-8t]
        unsigned csum = 0;
#pragma unroll
        for (int j = 0; j < 8; j++) csum += hist[4095 - 8 * t - j];
        ssc[t] = csum; __syncthreads();
        for (int off = 1; off < 512; off <<= 1) {
            unsigned x = (t >= off) ? ssc[t - off] : 0u;
            __syncthreads(); ssc[t] += x; __syncthreads();
        }
        unsigned incl = ssc[t], excl = incl - csum;
        if (excl < (unsigned)k && incl >= (unsigned)k) {
            unsigned cum = excl;
#pragma unroll
            for (int j = 0; j < 8; j++) {
                int b = 4095 - 8 * t - j; unsigned h = hist[b];
                if (cum + h >= (unsigned)k) { s_d = b; s_rem = (int)((unsigned)k - cum); break; }
                cum += h;
            }
        }
        __syncthreads();
        const int d = s_d; const int rem0 = s_rem;

        // scan2: exact sum of bins>d, collect bin-d candidates
        float ms = 0.f;
        for (int i = t; i < N4; i += 512) {
            float4 q = v4[i];
#define HND(C) { unsigned b = __float_as_uint(C); int bn = (int)(b >> BSH); \
            if (bn > d) ms += (C); \
            else if (bn == d) { int ix = atomicAdd(&s_c, 1); if (ix < CAPL) cand[ix] = b; } }
            HND(q.x) HND(q.y) HND(q.z) HND(q.w)
#undef HND
        }
        __syncthreads();
        const int C = s_c;
        const bool okl = (C <= CAPL);

        // refine within bin d: 3 LDS-radix passes fix bits [17:0]
        unsigned cur = (unsigned)d << BSH; int rem = rem0;
        const int shs[3] = {11, 4, 0};
        const int wbs[3] = {7, 7, 4};
        for (int ps = 0; ps < 3; ps++) {
            const int sh = shs[ps], wb = wbs[ps], W = 1 << wb;
            if (t < W) rh[t] = 0;
            __syncthreads();
            if (okl) {
                for (int i = t; i < C; i += 512) {
                    unsigned b = cand[i];
                    if ((b >> (sh + wb)) == (cur >> (sh + wb)))
                        atomicAdd(&rh[(b >> sh) & (W - 1)], 1u);
                }
            } else {
                for (int i = t; i < PP; i += 512) {
                    unsigned b = __float_as_uint(v[i]);
                    if ((b >> (sh + wb)) == (cur >> (sh + wb)))
                        atomicAdd(&rh[(b >> sh) & (W - 1)], 1u);
                }
            }
            __syncthreads();
            if (t == 0) {
                unsigned cum = 0; int dd;
                for (dd = W - 1; dd > 0; --dd) {
                    unsigned h = rh[dd];
                    if (cum + h >= (unsigned)rem) break;
                    cum += h;
                }
                s_cur = cur | ((unsigned)dd << sh);
                s_rr = rem - (int)cum;
            }
            __syncthreads();
            cur = s_cur; rem = s_rr;
            __syncthreads();
        }
        const unsigned thr = cur;
        const float thrv = __uint_as_float(thr);

        float sg = ms, cg = 0.f;
        if (okl) {
            for (int i = t; i < C; i += 512) {
                unsigned b = cand[i];
                if (b > thr) { sg += __uint_as_float(b); cg += 1.f; }
            }
        } else {
            for (int i = t; i < PP; i += 512) {
                unsigned b = __float_as_uint(v[i]);
                if ((int)(b >> BSH) == d && b > thr) { sg += __uint_as_float(b); cg += 1.f; }
            }
        }
#pragma unroll
        for (int dd = 32; dd > 0; dd >>= 1) {
            sg += __shfl_down(sg, dd);
            cg += __shfl_down(cg, dd);
        }
        if ((t & 63) == 0) { wred[wave] = sg; wred2[wave] = cg; }
        __syncthreads();
        if (t == 0) {
            float S = 0.f, Cc = 0.f;
            for (int i = 0; i < 8; i++) { S += wred[i]; Cc += wred2[i]; }
            result = S + ((float)rem0 - Cc) * thrv;
        }
    }

    // ---- last of 32 blocks finalizes ----
    if (t == 0) {
        hn[n] = result;
        __threadfence();
        int old = atomicAdd(done, 1);
        if (old == NB - 1) {
            int np = 0, den = 0; float hs = 0.f;
            for (int i = 0; i < NB; i++) {
                int c = pcnt[i];
                np += c;
                int kk = c * 3; if (kk > PP) kk = PP;
                den += kk;
                hs += hn[i];
            }
            float npf = (float)np;
            out[0] = acc[1] / npf + acc[2] / npf
                   + hs / fmaxf((float)den, 1.0f)
                   + acc[0] / (npf * 4.0f);
        }
    }
}

extern "C" void kernel_launch(void* const* d_in, const int* in_sizes, int n_in,
                              void* d_out, int out_size, void* d_ws, size_t ws_size,
                              hipStream_t stream) {
    const float* pred_boxes = (const float*)d_in[0];
    const float* pred_cls   = (const float*)d_in[1];
    const float* pred_obj   = (const float*)d_in[2];
    const float* priors     = (const float*)d_in[3];
    const float* boxes      = (const float*)d_in[4];
    const int*   labels     = (const int*)d_in[5];

    char* ws = (char*)d_ws;
    float* acc = (float*)(ws + WS_ACC);
    int* done  = (int*)(ws + WS_DONE);
    int* pcnt  = (int*)(ws + WS_PCNT);
    float* hn  = (float*)(ws + WS_HN);
    int* cpart = (int*)(ws + WS_CPART);
    unsigned long long* bkeyp = (unsigned long long*)(ws + WS_BKEYP);
    unsigned* posbit = (unsigned*)(ws + WS_POSBIT);
    unsigned char* m8 = (unsigned char*)(ws + WS_M8);
    float* val = (float*)(ws + WS_VAL);

    k_match<<<dim3(MBLK, NB), 256, 0, stream>>>(priors, boxes, pred_obj, bkeyp,
                                                posbit, m8, val, cpart, acc, done);
    k_ce<<<dim3(CEX, NB), 1024, 0, stream>>>(pred_boxes, pred_cls, pred_obj,
                                             priors, boxes, labels, m8, posbit,
                                             bkeyp, acc);
    k_sel<<<NB, 512, 0, stream>>>(bkeyp, posbit, cpart, val, pcnt, hn, acc, done,
                                  (float*)d_out);
}

// Round 10
// 82.546 us; speedup vs baseline: 7.5045x; 1.2189x over previous
//
#include <hip/hip_runtime.h>
#include <math.h>

#define NB 32
#define PP 24564
#define MM 32
#define NCLS 81
#define CHUNK 1024
#define MBLK 24          // ceil(PP/CHUNK)
#define PPW 768          // posbit u32 words per image
#define BSH 18           // bin = float_bits >> 18 (4096 bins)
#define HB 4096
#define CAPL 2048        // LDS candidate cap in k_fin

// ---- workspace layout (bytes); nothing pre-zeroed by host ----
#define WS_DONE   0        // int (zeroed by k_match block (0,0))
#define WS_PCNT   32       // int[NB] (k_fin writes)
#define WS_IACC   160      // float4[NB]: {ce,loc,op,hn} (k_fin writes)
#define WS_PACC   672      // float[NB*MBLK*3] (k_match plain stores) -> ends 9888
#define WS_CPART  9888     // int[NB*MBLK] (k_match plain stores) -> ends 12960
#define WS_BKEYP  12960    // u64[NB*MBLK*MM] -> ends 209568
#define WS_POSBIT 209568   // u32[NB*PPW] -> ends 307872
#define WS_M8     307872   // u8[NB*PP] -> ends 1093920
#define WS_VAL    1093936  // float[NB*PP] 16B-aligned -> ends ~4.24MB

__device__ __forceinline__ float sl1(float d) {
    float a = fabsf(d);
    return a < 1.0f ? 0.5f * d * d : a - 0.5f;
}
__device__ __forceinline__ unsigned long long u64max(unsigned long long a, unsigned long long b) {
    return a > b ? a : b;
}
__device__ __forceinline__ float locv(const float4& pd, const float4& pb,
                                      float gx1, float gy1, float gx2, float gy2) {
    float pcx = (pb.x + pb.z) * 0.5f, pcy = (pb.y + pb.w) * 0.5f;
    float pw = pb.z - pb.x, ph = pb.w - pb.y;
    float g0 = ((gx1 + gx2) * 0.5f - pcx) / (pw / 10.0f);
    float g1 = ((gy1 + gy2) * 0.5f - pcy) / (ph / 10.0f);
    float g2 = logf((gx2 - gx1) / pw) * 5.0f;
    float g3 = logf((gy2 - gy1) / ph) * 5.0f;
    return sl1(pd.x - g0) + sl1(pd.y - g1) + sl1(pd.z - g2) + sl1(pd.w - g3);
}

// ---------- matching + natural-positive losses fused ----------
extern "C" __global__ void __launch_bounds__(256) k_match(
    const float* __restrict__ priors,
    const float* __restrict__ boxes,
    const float* __restrict__ obj,
    const float* __restrict__ pred_boxes,
    const float* __restrict__ pred_cls,
    const int* __restrict__ labels,
    unsigned long long* __restrict__ bkeyp,
    unsigned int* __restrict__ posbit,
    unsigned char* __restrict__ m8,
    float* __restrict__ val,
    int* __restrict__ cpart,
    float* __restrict__ pacc,
    int* __restrict__ done)
{
    const int n = blockIdx.y;
    const int t = threadIdx.x;
    const int lane = t & 63;
    const int wave = t >> 6;
    const int bx = blockIdx.x;
    const int p0 = bx * CHUNK;

    if (bx == 0 && n == 0 && t == 0) *done = 0;

    __shared__ float4 spri[CHUNK];
    __shared__ unsigned char sm8[CHUNK];
    __shared__ float bx0[MM], by0[MM], bx1[MM], by1[MM], bar_[MM];
    __shared__ unsigned long long wk[4][MM];
    __shared__ int bcnt;
    __shared__ float sacc[3];

    float ov[4];
#pragma unroll
    for (int i = 0; i < 4; i++) {
        int p = p0 + t + i * 256;
        float4 v;
        if (p < PP) { v = *(const float4*)(priors + (size_t)p * 4);
                      ov[i] = obj[(size_t)n * PP + p]; }
        else { v.x = 3.f; v.y = 3.f; v.z = 3.5f; v.w = 3.5f; ov[i] = 0.f; }
        spri[t + i * 256] = v;
    }
    if (t < MM) {
        const float* b = boxes + ((size_t)n * MM + t) * 4;
        float x1 = b[0], y1 = b[1], x2 = b[2], y2 = b[3];
        bx0[t] = x1; by0[t] = y1; bx1[t] = x2; by1[t] = y2;
        bar_[t] = (x2 - x1) * (y2 - y1);
    }
    if (t == 0) bcnt = 0;
    if (t < 3) sacc[t] = 0.f;
    __syncthreads();

    float4 pr0 = spri[t], pr1 = spri[t + 256], pr2 = spri[t + 512], pr3 = spri[t + 768];
    const float pa0 = (pr0.z - pr0.x) * (pr0.w - pr0.y);
    const float pa1 = (pr1.z - pr1.x) * (pr1.w - pr1.y);
    const float pa2 = (pr2.z - pr2.x) * (pr2.w - pr2.y);
    const float pa3 = (pr3.z - pr3.x) * (pr3.w - pr3.y);
    unsigned pb0 = 0, pb1 = 0, pb2 = 0, pb3 = 0;

#define DO_IOU(PR, PA, PB, ROFF) { \
        float w = fminf(x1, PR.z) - fmaxf(x0, PR.x); \
        float h = fminf(y1, PR.w) - fmaxf(y0, PR.y); \
        w = fmaxf(w, 0.0f); h = fmaxf(h, 0.0f); \
        float inter = w * h; \
        float iou = inter / (ar + PA - inter); \
        unsigned ib = __float_as_uint(iou); \
        unsigned nk = (ib & 0xFFFFFFE0u) | (unsigned)(31 - m); \
        PB = PB > nk ? PB : nk; \
        unsigned long long kk = ((unsigned long long)ib << 32) \
            | (unsigned long long)(0xFFFFFFFFu - (unsigned)(p0 + t + (ROFF))); \
        km = u64max(km, kk); }

#pragma unroll 2
    for (int m = 0; m < MM; m++) {
        const float x0 = bx0[m], y0 = by0[m], x1 = bx1[m], y1 = by1[m], ar = bar_[m];
        unsigned long long km = 0ULL;
        DO_IOU(pr0, pa0, pb0, 0)
        DO_IOU(pr1, pa1, pb1, 256)
        DO_IOU(pr2, pa2, pb2, 512)
        DO_IOU(pr3, pa3, pb3, 768)
#pragma unroll
        for (int d = 1; d < 64; d <<= 1)
            km = u64max(km, (unsigned long long)__shfl_xor(km, d));
        if (lane == 0) wk[wave][m] = km;
    }
#undef DO_IOU

    int cnt = 0;
    unsigned long long bl[4];
#define ROWOUT(PB, R) { \
        int p = p0 + t + (R) * 256; \
        bool pos = (PB >= 0x3F000000u) && (p < PP); \
        unsigned long long ball = __ballot(pos); \
        bl[R] = ball; \
        unsigned char mb = (unsigned char)(31u - (PB & 31u)); \
        sm8[t + (R) * 256] = mb; \
        if (lane == 0) { \
            int wi = n * PPW + ((p0 + (R) * 256 + wave * 64) >> 5); \
            posbit[wi] = (unsigned)ball; posbit[wi + 1] = (unsigned)(ball >> 32); \
            cnt += __popcll(ball); \
        } \
        if (p < PP) { \
            size_t idx = (size_t)n * PP + p; \
            m8[idx] = mb; \
            val[idx] = pos ? 0.f : ov[R] * ov[R]; \
        } }
    ROWOUT(pb0, 0) ROWOUT(pb1, 1) ROWOUT(pb2, 2) ROWOUT(pb3, 3)
#undef ROWOUT
    if (lane == 0 && cnt) atomicAdd(&bcnt, cnt);

    // ---- natural-positive losses inline (half-wave per positive) ----
    {
        const int half = lane >> 5, hl = lane & 31;
        float ce_s = 0.f, loc_s = 0.f, op_s = 0.f;
#pragma unroll
        for (int R = 0; R < 4; R++) {
            unsigned long long mask = bl[R];
            const int roff = R * 256 + wave * 64;
            while (mask) {
                int i1 = __ffsll((long long)mask) - 1; mask &= mask - 1;
                int i2 = -1;
                if (mask) { i2 = __ffsll((long long)mask) - 1; mask &= mask - 1; }
                const int pi = half ? i2 : i1;
                const bool act = pi >= 0;
                const int poff = roff + (act ? pi : 0);
                const size_t idx = (size_t)n * PP + p0 + poff;

                const int bm = sm8[poff];
                const float* row = pred_cls + idx * NCLS;
                float a = act ? row[hl] : -INFINITY;
                float b = act ? row[hl + 32] : -INFINITY;
                float c = (act && hl < NCLS - 64) ? row[hl + 64] : -INFINITY;
                float mx = fmaxf(fmaxf(a, b), c);
#pragma unroll
                for (int d = 1; d < 32; d <<= 1) mx = fmaxf(mx, __shfl_xor(mx, d));
                float se = act ? (expf(a - mx) + expf(b - mx)
                                  + ((hl < NCLS - 64) ? expf(c - mx) : 0.f)) : 0.f;
#pragma unroll
                for (int d = 1; d < 32; d <<= 1) se += __shfl_xor(se, d);

                if (act) {
                    if (hl == 0) {
                        ce_s += mx + logf(se) - row[labels[n * MM + bm]];
                    } else if (hl == 1) {
                        float4 pb = spri[poff];
                        float4 pd = *(const float4*)(pred_boxes + idx * 4);
                        loc_s += locv(pd, pb, bx0[bm], by0[bm], bx1[bm], by1[bm]);
                    } else if (hl == 2) {
                        float o = obj[idx];
                        op_s += (o - 1.0f) * (o - 1.0f);
                    }
                }
            }
        }
        if (ce_s != 0.f)  atomicAdd(&sacc[0], ce_s);
        if (loc_s != 0.f) atomicAdd(&sacc[1], loc_s);
        if (op_s != 0.f)  atomicAdd(&sacc[2], op_s);
    }

    __syncthreads();
    if (t == 0) {
        cpart[n * MBLK + bx] = bcnt;
        float* pa = pacc + ((size_t)n * MBLK + bx) * 3;
        pa[0] = sacc[0]; pa[1] = sacc[1]; pa[2] = sacc[2];
    }
    if (t < MM) {
        unsigned long long r = u64max(u64max(wk[0][t], wk[1][t]),
                                      u64max(wk[2][t], wk[3][t]));
        bkeyp[((size_t)n * MBLK + bx) * MM + t] = r;
    }
}

// ---------- forced fixups + partial-sum + top-k selection + finalize ----------
extern "C" __global__ void __launch_bounds__(512) k_fin(
    const float* __restrict__ priors,
    const float* __restrict__ boxes,
    const float* __restrict__ obj,
    const float* __restrict__ pred_boxes,
    const float* __restrict__ pred_cls,
    const int* __restrict__ labels,
    const unsigned long long* __restrict__ bkeyp,
    const unsigned int* __restrict__ posbit,
    const unsigned char* __restrict__ m8,
    const int* __restrict__ cpart,
    const float* __restrict__ pacc,
    float* __restrict__ val,
    int* __restrict__ pcnt,
    float4* __restrict__ iacc,
    int* __restrict__ done,
    float* __restrict__ out)
{
    const int n = blockIdx.x;
    const int t = threadIdx.x;
    const int lane = t & 63;
    const int wave = t >> 6;
    float* v = val + (size_t)n * PP;
    const float4* v4 = (const float4*)v;
    const int N4 = PP / 4;

    __shared__ unsigned fl[MM];
    __shared__ int newlist[MM];
    __shared__ int s_nnew, s_nat, s_tot;
    __shared__ float sacc[3];
    __shared__ float wred[8], wred2[8];

    if (t < 3) sacc[t] = 0.f;
    if (t == 0) { s_nnew = 0; s_nat = 0; }
    __syncthreads();

    if (t < MM) {
        const unsigned long long* bp = bkeyp + (size_t)n * MBLK * MM + t;
        unsigned long long r = 0ULL;
#pragma unroll
        for (int s = 0; s < MBLK; s++) r = u64max(r, bp[(size_t)s * MM]);
        fl[t] = ~(unsigned)(r & 0xFFFFFFFFULL);
    }
    if (t < MBLK) atomicAdd(&s_nat, cpart[n * MBLK + t]);
    __syncthreads();

    float d_ce = 0.f, d_loc = 0.f;
    if (t < MM) {
        unsigned p = fl[t];
        bool owner = true;
        for (int j = t + 1; j < MM; j++) if (fl[j] == p) owner = false;
        if (owner) {
            size_t idx = (size_t)n * PP + p;
            bool natPos = (posbit[n * PPW + (p >> 5)] >> (p & 31)) & 1u;
            if (natPos) {
                int bmn = (int)m8[idx];
                if (bmn != t) {
                    const float* row = pred_cls + idx * NCLS;
                    d_ce = row[labels[n * MM + bmn]] - row[labels[n * MM + t]];
                    float4 pb = *(const float4*)(priors + (size_t)p * 4);
                    float4 pd = *(const float4*)(pred_boxes + idx * 4);
                    const float* bf = boxes + ((size_t)n * MM + t) * 4;
                    const float* bn = boxes + ((size_t)n * MM + bmn) * 4;
                    d_loc = locv(pd, pb, bf[0], bf[1], bf[2], bf[3])
                          - locv(pd, pb, bn[0], bn[1], bn[2], bn[3]);
                }
            } else {
                int ix = atomicAdd(&s_nnew, 1);
                newlist[ix] = ((int)p << 5) | t;
                v[p] = 0.f;
            }
        }
    }
    if (t < 64) {
#pragma unroll
        for (int d = 1; d < 64; d <<= 1) {
            d_ce += __shfl_xor(d_ce, d);
            d_loc += __shfl_xor(d_loc, d);
        }
        if (t == 0) {
            if (d_ce != 0.f)  atomicAdd(&sacc[0], d_ce);
            if (d_loc != 0.f) atomicAdd(&sacc[1], d_loc);
        }
    }
    if (t < MBLK * 3) atomicAdd(&sacc[t % 3], pacc[(size_t)n * MBLK * 3 + t]);
    __syncthreads();

    const int nn = s_nnew;
    {
        const int hl = lane & 31;
        float nce = 0.f, nloc = 0.f, nop = 0.f;
        for (int i = wave; i < nn; i += 8) {
            int e = newlist[i];
            int p = e >> 5, bm = e & 31;
            size_t idx = (size_t)n * PP + p;
            const float* row = pred_cls + idx * NCLS;
            bool al = lane < 32;
            float a = al ? row[hl] : -INFINITY;
            float b = al ? row[hl + 32] : -INFINITY;
            float c = (al && hl < NCLS - 64) ? row[hl + 64] : -INFINITY;
            float mx = fmaxf(fmaxf(a, b), c);
#pragma unroll
            for (int d = 1; d < 32; d <<= 1) mx = fmaxf(mx, __shfl_xor(mx, d));
            float se = al ? (expf(a - mx) + expf(b - mx)
                             + ((hl < NCLS - 64) ? expf(c - mx) : 0.f)) : 0.f;
#pragma unroll
            for (int d = 1; d < 32; d <<= 1) se += __shfl_xor(se, d);
            if (lane == 0) {
                nce += mx + logf(se) - row[labels[n * MM + bm]];
            } else if (lane == 1) {
                float4 pb = *(const float4*)(priors + (size_t)p * 4);
                float4 pd = *(const float4*)(pred_boxes + idx * 4);
                const float* bb = boxes + ((size_t)n * MM + bm) * 4;
                nloc += locv(pd, pb, bb[0], bb[1], bb[2], bb[3]);
            } else if (lane == 2) {
                float o = obj[idx];
                nop += (o - 1.0f) * (o - 1.0f);
            }
        }
        if (nce != 0.f)  atomicAdd(&sacc[0], nce);
        if (nloc != 0.f) atomicAdd(&sacc[1], nloc);
        if (nop != 0.f)  atomicAdd(&sacc[2], nop);
    }
    __syncthreads();
    if (t == 0) s_tot = s_nat + s_nnew;
    __syncthreads();
    int k = s_tot * 3; if (k > PP) k = PP;

    float result = 0.f;
    if (k >= PP) {
        float s = 0.f;
        for (int i = t; i < N4; i += 512) {
            float4 q = v4[i]; s += q.x + q.y + q.z + q.w;
        }
#pragma unroll
        for (int d = 32; d > 0; d >>= 1) s += __shfl_down(s, d);
        if ((t & 63) == 0) wred[wave] = s;
        __syncthreads();
        if (t == 0) { for (int i = 0; i < 8; i++) result += wred[i]; }
    } else if (k > 0) {
        __shared__ unsigned hist[HB];
        __shared__ unsigned ssc[512];
        __shared__ unsigned cand[CAPL];
        __shared__ int s_c, s_d, s_rem;
        __shared__ unsigned s_cur;
        __shared__ int s_rr;
        __shared__ unsigned rh[128];

        for (int i = t; i < HB; i += 512) hist[i] = 0;
        if (t == 0) s_c = 0;
        __syncthreads();

        for (int i = t; i < N4; i += 512) {
            float4 q = v4[i];
            atomicAdd(&hist[__float_as_uint(q.x) >> BSH], 1u);
            atomicAdd(&hist[__float_as_uint(q.y) >> BSH], 1u);
            atomicAdd(&hist[__float_as_uint(q.z) >> BSH], 1u);
            atomicAdd(&hist[__float_as_uint(q.w) >> BSH], 1u);
        }
        __syncthreads();

        unsigned csum = 0;
#pragma unroll
        for (int j = 0; j < 8; j++) csum += hist[4095 - 8 * t - j];
        ssc[t] = csum; __syncthreads();
        for (int off = 1; off < 512; off <<= 1) {
            unsigned x = (t >= off) ? ssc[t - off] : 0u;
            __syncthreads(); ssc[t] += x; __syncthreads();
        }
        unsigned incl = ssc[t], excl = incl - csum;
        if (excl < (unsigned)k && incl >= (unsigned)k) {
            unsigned cum = excl;
#pragma unroll
            for (int j = 0; j < 8; j++) {
                int b = 4095 - 8 * t - j; unsigned h = hist[b];
                if (cum + h >= (unsigned)k) { s_d = b; s_rem = (int)((unsigned)k - cum); break; }
                cum += h;
            }
        }
        __syncthreads();
        const int d = s_d; const int rem0 = s_rem;

        float ms = 0.f;
        for (int i = t; i < N4; i += 512) {
            float4 q = v4[i];
#define HND(C) { unsigned b = __float_as_uint(C); int bn = (int)(b >> BSH); \
            if (bn > d) ms += (C); \
            else if (bn == d) { int ix = atomicAdd(&s_c, 1); if (ix < CAPL) cand[ix] = b; } }
            HND(q.x) HND(q.y) HND(q.z) HND(q.w)
#undef HND
        }
        __syncthreads();
        const int C = s_c;
        const bool okl = (C <= CAPL);

        unsigned cur = (unsigned)d << BSH; int rem = rem0;
        const int shs[3] = {11, 4, 0};
        const int wbs[3] = {7, 7, 4};
        for (int ps = 0; ps < 3; ps++) {
            const int sh = shs[ps], wb = wbs[ps], W = 1 << wb;
            if (t < W) rh[t] = 0;
            __syncthreads();
            if (okl) {
                for (int i = t; i < C; i += 512) {
                    unsigned b = cand[i];
                    if ((b >> (sh + wb)) == (cur >> (sh + wb)))
                        atomicAdd(&rh[(b >> sh) & (W - 1)], 1u);
                }
            } else {
                for (int i = t; i < PP; i += 512) {
                    unsigned b = __float_as_uint(v[i]);
                    if ((b >> (sh + wb)) == (cur >> (sh + wb)))
                        atomicAdd(&rh[(b >> sh) & (W - 1)], 1u);
                }
            }
            __syncthreads();
            if (t == 0) {
                unsigned cum = 0; int dd;
                for (dd = W - 1; dd > 0; --dd) {
                    unsigned h = rh[dd];
                    if (cum + h >= (unsigned)rem) break;
                    cum += h;
                }
                s_cur = cur | ((unsigned)dd << sh);
                s_rr = rem - (int)cum;
            }
            __syncthreads();
            cur = s_cur; rem = s_rr;
            __syncthreads();
        }
        const unsigned thr = cur;
        const float thrv = __uint_as_float(thr);

        float sg = ms, cg = 0.f;
        if (okl) {
            for (int i = t; i < C; i += 512) {
                unsigned b = cand[i];
                if (b > thr) { sg += __uint_as_float(b); cg += 1.f; }
            }
        } else {
            for (int i = t; i < PP; i += 512) {
                unsigned b = __float_as_uint(v[i]);
                if ((int)(b >> BSH) == d && b > thr) { sg += __uint_as_float(b); cg += 1.f; }
            }
        }
#pragma unroll
        for (int dd = 32; dd > 0; dd >>= 1) {
            sg += __shfl_down(sg, dd);
            cg += __shfl_down(cg, dd);
        }
        if ((t & 63) == 0) { wred[wave] = sg; wred2[wave] = cg; }
        __syncthreads();
        if (t == 0) {
            float S = 0.f, Cc = 0.f;
            for (int i = 0; i < 8; i++) { S += wred[i]; Cc += wred2[i]; }
            result = S + ((float)rem0 - Cc) * thrv;
        }
    }

    if (t == 0) {
        pcnt[n] = s_tot;
        iacc[n] = make_float4(sacc[0], sacc[1], sacc[2], result);
        __threadfence();
        int old = atomicAdd(done, 1);
        if (old == NB - 1) {
            int np = 0, den = 0; float ce = 0.f, lc = 0.f, op = 0.f, hs = 0.f;
            for (int i = 0; i < NB; i++) {
                int c = pcnt[i];
                np += c;
                int kk = c * 3; if (kk > PP) kk = PP;
                den += kk;
                float4 a = iacc[i];
                ce += a.x; lc += a.y; op += a.z; hs += a.w;
            }
            float npf = (float)np;
            out[0] = ce / npf + op / npf
                   + hs / fmaxf((float)den, 1.0f)
                   + lc / (npf * 4.0f);
        }
    }
}

extern "C" void kernel_launch(void* const* d_in, const int* in_sizes, int n_in,
                              void* d_out, int out_size, void* d_ws, size_t ws_size,
                              hipStream_t stream) {
    const float* pred_boxes = (const float*)d_in[0];
    const float* pred_cls   = (const float*)d_in[1];
    const float* pred_obj   = (const float*)d_in[2];
    const float* priors     = (const float*)d_in[3];
    const float* boxes      = (const float*)d_in[4];
    const int*   labels     = (const int*)d_in[5];

    char* ws = (char*)d_ws;
    int* done  = (int*)(ws + WS_DONE);
    int* pcnt  = (int*)(ws + WS_PCNT);
    float4* iacc = (float4*)(ws + WS_IACC);
    float* pacc = (float*)(ws + WS_PACC);
    int* cpart = (int*)(ws + WS_CPART);
    unsigned long long* bkeyp = (unsigned long long*)(ws + WS_BKEYP);
    unsigned* posbit = (unsigned*)(ws + WS_POSBIT);
    unsigned char* m8 = (unsigned char*)(ws + WS_M8);
    float* val = (float*)(ws + WS_VAL);

    k_match<<<dim3(MBLK, NB), 256, 0, stream>>>(priors, boxes, pred_obj, pred_boxes,
                                                pred_cls, labels, bkeyp, posbit, m8,
                                                val, cpart, pacc, done);
    k_fin<<<NB, 512, 0, stream>>>(priors, boxes, pred_obj, pred_boxes, pred_cls,
                                  labels, bkeyp, posbit, m8, cpart, pacc, val,
                                  pcnt, iacc, done, (float*)d_out);
}